// Round 3
// baseline (443.916 us; speedup 1.0000x reference)
//
#include <hip/hip_runtime.h>

#define BB    32
#define NSEQ  1024
#define CDIM  768
#define NH    12
#define HD    64
#define LKEYS 128
#define NPOOL 128

typedef __bf16 bf16x8 __attribute__((ext_vector_type(8)));
typedef float  f32x4  __attribute__((ext_vector_type(4)));

__device__ __forceinline__ ushort f2bf(float f) {
    union { float f; uint u; } v; v.f = f;
    uint u = v.u;
    uint r = u + 0x7FFFu + ((u >> 16) & 1u);   // RNE
    return (ushort)(r >> 16);
}
__device__ __forceinline__ uint pack2(float x, float y) {
    return (uint)f2bf(x) | ((uint)f2bf(y) << 16);
}

// ---------------------------------------------------------------------------
// 0a) fp32 -> bf16 bulk convert
// ---------------------------------------------------------------------------
__global__ __launch_bounds__(256) void cvt_bf16_kernel(const float* __restrict__ src,
                                                       ushort* __restrict__ dst, int n8)
{
    int idx = blockIdx.x * 256 + threadIdx.x;
    if (idx >= n8) return;
    float4 a = ((const float4*)src)[idx * 2];
    float4 b = ((const float4*)src)[idx * 2 + 1];
    uint4 o;
    o.x = pack2(a.x, a.y); o.y = pack2(a.z, a.w);
    o.z = pack2(b.x, b.y); o.w = pack2(b.z, b.w);
    ((uint4*)dst)[idx] = o;
}

// ---------------------------------------------------------------------------
// 0b) transpose + convert
// ---------------------------------------------------------------------------
__global__ __launch_bounds__(256) void transpose_cvt_kernel(const float* __restrict__ src,
                                                            ushort* __restrict__ dst,
                                                            int R, int C)
{
    __shared__ ushort tile[32][33];
    int bc = blockIdx.x * 32, br = blockIdx.y * 32;
    int tx = threadIdx.x & 31, ty = threadIdx.x >> 5;
#pragma unroll
    for (int i = 0; i < 32; i += 8)
        tile[ty + i][tx] = f2bf(src[(size_t)(br + ty + i) * C + bc + tx]);
    __syncthreads();
#pragma unroll
    for (int i = 0; i < 32; i += 8)
        dst[(size_t)(bc + ty + i) * R + br + tx] = tile[tx][ty + i];
}

// ---------------------------------------------------------------------------
// 1) pool
// ---------------------------------------------------------------------------
__global__ __launch_bounds__(256) void pool_kernel(const float* __restrict__ x,
                                                   ushort* __restrict__ xp)
{
    int idx = blockIdx.x * 256 + threadIdx.x;
    int c8 = idx % 96;
    int t  = idx / 96;
    int i  = t % NPOOL;
    int b  = t / NPOOL;
    if (b >= BB) return;
    const float4* x4 = (const float4*)x;
    size_t base0 = ((size_t)(b * NSEQ + 2 * i)) * 192 + c8 * 2;
    size_t base1 = base0 + 192;
    float4 a0 = x4[base0], a1 = x4[base0 + 1];
    float4 b0 = x4[base1], b1 = x4[base1 + 1];
    uint4 o;
    o.x = pack2(0.5f * (a0.x + b0.x), 0.5f * (a0.y + b0.y));
    o.y = pack2(0.5f * (a0.z + b0.z), 0.5f * (a0.w + b0.w));
    o.z = pack2(0.5f * (a1.x + b1.x), 0.5f * (a1.y + b1.y));
    o.w = pack2(0.5f * (a1.z + b1.z), 0.5f * (a1.w + b1.w));
    ((uint4*)xp)[idx] = o;
}

// ---------------------------------------------------------------------------
// 2a) 128^2-tile bf16 MFMA GEMM (m97 structure) — kept for KV proj (skinny grid)
// ---------------------------------------------------------------------------
template <bool OBF16>
__global__ __launch_bounds__(256) void mfma_gemm_kernel(
    const ushort* __restrict__ A, const ushort* __restrict__ Bt,
    const float* __restrict__ bias, void* __restrict__ Cout,
    int M, int N, int K)
{
    __shared__ ushort As[128 * 32];
    __shared__ ushort Bs[128 * 32];

    int tid  = threadIdx.x;
    int wave = tid >> 6, lane = tid & 63;

    int nwg  = gridDim.x * gridDim.y;
    int bid  = blockIdx.y * gridDim.x + blockIdx.x;
    int q    = nwg >> 3, r = nwg & 7;
    int xcd  = bid & 7, j = bid >> 3;
    int flat = (xcd < r ? xcd * (q + 1) : r * (q + 1) + (xcd - r) * q) + j;
    int n0 = (flat % gridDim.x) * 128;
    int m0 = (flat / gridDim.x) * 128;

    int wm = wave >> 1, wn = wave & 1;
    int lm = lane & 15, lh = lane >> 4;

    f32x4 acc[4][4] = {};

    for (int k0 = 0; k0 < K; k0 += 32) {
        __syncthreads();
#pragma unroll
        for (int t = 0; t < 2; t++) {
            int fl = wave * 128 + t * 64 + lane;
            int row = fl >> 2, kc = (fl & 3) * 8;
            const ushort* gA = A  + (size_t)(m0 + row) * K + k0 + kc;
            const ushort* gB = Bt + (size_t)(n0 + row) * K + k0 + kc;
            __builtin_amdgcn_global_load_lds(
                (const __attribute__((address_space(1))) void*)gA,
                (__attribute__((address_space(3))) void*)(As + (size_t)(wave * 128 + t * 64) * 8),
                16, 0, 0);
            __builtin_amdgcn_global_load_lds(
                (const __attribute__((address_space(1))) void*)gB,
                (__attribute__((address_space(3))) void*)(Bs + (size_t)(wave * 128 + t * 64) * 8),
                16, 0, 0);
        }
        __syncthreads();

        bf16x8 af[4], bfr[4];
#pragma unroll
        for (int i = 0; i < 4; i++)
            af[i] = *(const bf16x8*)((const void*)&As[(wm * 64 + i * 16 + lm) * 32 + lh * 8]);
#pragma unroll
        for (int jj = 0; jj < 4; jj++)
            bfr[jj] = *(const bf16x8*)((const void*)&Bs[(wn * 64 + jj * 16 + lm) * 32 + lh * 8]);
#pragma unroll
        for (int i = 0; i < 4; i++)
#pragma unroll
            for (int jj = 0; jj < 4; jj++)
                acc[i][jj] = __builtin_amdgcn_mfma_f32_16x16x32_bf16(af[i], bfr[jj], acc[i][jj], 0, 0, 0);
    }

    int crow = m0 + wm * 64, ccol = n0 + wn * 64;
#pragma unroll
    for (int jj = 0; jj < 4; jj++) {
        int col = ccol + jj * 16 + lm;
        float bb = bias[col];
        if constexpr (OBF16) {
            ushort* C = (ushort*)Cout;
#pragma unroll
            for (int i = 0; i < 4; i++)
#pragma unroll
                for (int rr = 0; rr < 4; rr++)
                    C[(size_t)(crow + i * 16 + lh * 4 + rr) * N + col] = f2bf(acc[i][jj][rr] + bb);
        } else {
            float* C = (float*)Cout;
#pragma unroll
            for (int i = 0; i < 4; i++)
#pragma unroll
                for (int rr = 0; rr < 4; rr++)
                    C[(size_t)(crow + i * 16 + lh * 4 + rr) * N + col] = acc[i][jj][rr] + bb;
        }
    }
}

// ---------------------------------------------------------------------------
// 2b) 256^2-tile deep-pipelined GEMM (T2+T3+T4+T5).
//    512 thr = 8 waves (2M x 4N), wave-out 128x64, BK=32, depth-4 circular
//    LDS (4 x 32 KB = 128 KiB), counted vmcnt (10/8/4/0), XOR chunk swizzle
//    pch = lh ^ ((row>>1)&3) applied on BOTH the pre-swizzled global source
//    (linear global_load_lds dest) and the ds_read side (rule 21).
//    Requires M%256==0, N%256==0, K%32==0.
// ---------------------------------------------------------------------------
template <bool OBF16>
__global__ __launch_bounds__(512) void gemm256_kernel(
    const ushort* __restrict__ A, const ushort* __restrict__ Bt,
    const float* __restrict__ bias, void* __restrict__ Cout,
    int M, int N, int K)
{
    __shared__ ushort As[4][256 * 32];   // 4 x 16 KB
    __shared__ ushort Bs[4][256 * 32];   // 4 x 16 KB

    int tid  = threadIdx.x;
    int lane = tid & 63;
    int wave = tid >> 6;

    // XCD-aware bijective swizzle (T1)
    int nwg  = gridDim.x * gridDim.y;
    int bid  = blockIdx.y * gridDim.x + blockIdx.x;
    int q    = nwg >> 3, r = nwg & 7;
    int xcd  = bid & 7, j = bid >> 3;
    int flat = (xcd < r ? xcd * (q + 1) : r * (q + 1) + (xcd - r) * q) + j;
    int n0 = (flat % gridDim.x) * 256;
    int m0 = (flat / gridDim.x) * 256;

    int wm = wave >> 2, wn = wave & 3;       // 2 x 4
    int lm = lane & 15, lh = lane >> 4;

    int NT = K >> 5;                          // K-tiles of 32

    auto stageA = [&](int tt) {
        int slot = tt & 3;
#pragma unroll
        for (int ld = 0; ld < 2; ld++) {
            int fl = ld * 512 + tid;          // 0..1023 16B-chunks
            int prow = fl >> 2, pch = fl & 3;
            int lch  = pch ^ ((prow >> 1) & 3);
            const ushort* g = A + (size_t)(m0 + prow) * K + tt * 32 + lch * 8;
            __builtin_amdgcn_global_load_lds(
                (const __attribute__((address_space(1))) void*)g,
                (__attribute__((address_space(3))) void*)(&As[slot][fl * 8]),
                16, 0, 0);
        }
    };
    auto stageB = [&](int tt) {
        int slot = tt & 3;
#pragma unroll
        for (int ld = 0; ld < 2; ld++) {
            int fl = ld * 512 + tid;
            int prow = fl >> 2, pch = fl & 3;
            int lch  = pch ^ ((prow >> 1) & 3);
            const ushort* g = Bt + (size_t)(n0 + prow) * K + tt * 32 + lch * 8;
            __builtin_amdgcn_global_load_lds(
                (const __attribute__((address_space(1))) void*)g,
                (__attribute__((address_space(3))) void*)(&Bs[slot][fl * 8]),
                16, 0, 0);
        }
    };

    f32x4 acc[8][4] = {};

    // prologue: prefetch tiles 0,1,2
    stageA(0); stageB(0);
    stageA(1); stageB(1);
    stageA(2); stageB(2);

    for (int t = 0; t < NT; t++) {
        int slot = t & 3;

        // ---- phase 0: stage A(t+3), wait tile t resident, compute m-half 0
        if (t + 3 < NT) stageA(t + 3);

        if (t + 3 < NT)       asm volatile("s_waitcnt vmcnt(10)" ::: "memory");
        else if (t + 3 == NT) asm volatile("s_waitcnt vmcnt(8)"  ::: "memory");
        else if (t + 2 == NT) asm volatile("s_waitcnt vmcnt(4)"  ::: "memory");
        else                  asm volatile("s_waitcnt vmcnt(0)"  ::: "memory");
        __builtin_amdgcn_s_barrier();
        asm volatile("" ::: "memory");       // keep ds_reads below the barrier

        bf16x8 bfrag[4], afrag[4];
#pragma unroll
        for (int jj = 0; jj < 4; jj++) {
            int rn = wn * 64 + jj * 16 + lm;
            int pch = lh ^ ((rn >> 1) & 3);
            bfrag[jj] = *(const bf16x8*)((const void*)&Bs[slot][rn * 32 + pch * 8]);
        }
#pragma unroll
        for (int i = 0; i < 4; i++) {
            int rm = wm * 128 + i * 16 + lm;
            int pch = lh ^ ((rm >> 1) & 3);
            afrag[i] = *(const bf16x8*)((const void*)&As[slot][rm * 32 + pch * 8]);
        }
        __builtin_amdgcn_s_setprio(1);
#pragma unroll
        for (int i = 0; i < 4; i++)
#pragma unroll
            for (int jj = 0; jj < 4; jj++)
                acc[i][jj] = __builtin_amdgcn_mfma_f32_16x16x32_bf16(afrag[i], bfrag[jj], acc[i][jj], 0, 0, 0);
        __builtin_amdgcn_s_setprio(0);
        __builtin_amdgcn_s_barrier();

        // ---- phase 1: stage B(t+3), compute m-half 1
        if (t + 3 < NT) stageB(t + 3);
#pragma unroll
        for (int i = 0; i < 4; i++) {
            int rm = wm * 128 + 64 + i * 16 + lm;
            int pch = lh ^ ((rm >> 1) & 3);
            afrag[i] = *(const bf16x8*)((const void*)&As[slot][rm * 32 + pch * 8]);
        }
        __builtin_amdgcn_s_setprio(1);
#pragma unroll
        for (int i = 0; i < 4; i++)
#pragma unroll
            for (int jj = 0; jj < 4; jj++)
                acc[4 + i][jj] = __builtin_amdgcn_mfma_f32_16x16x32_bf16(afrag[i], bfrag[jj], acc[4 + i][jj], 0, 0, 0);
        __builtin_amdgcn_s_setprio(0);
        __builtin_amdgcn_s_barrier();        // all reads of slot t done -> slot reusable
    }

    // epilogue: wave-out 128 x 64; acc[i] row = (i>>2)*64 + (i&3)*16
    int crow = m0 + wm * 128, ccol = n0 + wn * 64;
#pragma unroll
    for (int jj = 0; jj < 4; jj++) {
        int col = ccol + jj * 16 + lm;
        float bb = bias[col];
        if constexpr (OBF16) {
            ushort* C = (ushort*)Cout;
#pragma unroll
            for (int i = 0; i < 8; i++) {
                int rowb = crow + (i >> 2) * 64 + (i & 3) * 16 + lh * 4;
#pragma unroll
                for (int rr = 0; rr < 4; rr++)
                    C[(size_t)(rowb + rr) * N + col] = f2bf(acc[i][jj][rr] + bb);
            }
        } else {
            float* C = (float*)Cout;
#pragma unroll
            for (int i = 0; i < 8; i++) {
                int rowb = crow + (i >> 2) * 64 + (i & 3) * 16 + lh * 4;
#pragma unroll
                for (int rr = 0; rr < 4; rr++)
                    C[(size_t)(rowb + rr) * N + col] = acc[i][jj][rr] + bb;
            }
        }
    }
}

// ---------------------------------------------------------------------------
// 3) compress + bank assembly -> bf16 outputs (k_full row-major, v_full^T)
// ---------------------------------------------------------------------------
__global__ __launch_bounds__(256) void compress_kernel(
    const float* __restrict__ kvp,
    const float* __restrict__ Ek, const float* __restrict__ Ev,
    const float* __restrict__ kbank, const float* __restrict__ vbank,
    ushort* __restrict__ kfull, ushort* __restrict__ vfullT)
{
    __shared__ float Es[128 * 64];
    __shared__ float Sl[128 * 64];

    int tid = threadIdx.x;
    int h = blockIdx.x, b = blockIdx.y, which = blockIdx.z;
    const float* E    = which ? Ev : Ek;
    const float* bank = which ? vbank : kbank;

#pragma unroll
    for (int i = 0; i < 8; i++) {
        int flat = tid + i * 256;
        *(float4*)&Es[flat * 4] = *(const float4*)&E[flat * 4];
    }
    const float* src = kvp + (size_t)b * 128 * 1536 + which * 768 + h * HD;
#pragma unroll
    for (int i = 0; i < 8; i++) {
        int flat = tid + i * 256;
        int s = flat >> 4, d4 = flat & 15;
        *(float4*)&Sl[s * 64 + d4 * 4] = *(const float4*)&src[(size_t)s * 1536 + d4 * 4];
    }

    const float* bankbase = bank + (size_t)b * 64 * CDIM + h * HD;
    ushort* outK = kfull  + (size_t)(b * NH + h) * LKEYS * HD;
    ushort* outV = vfullT + (size_t)(b * NH + h) * HD * LKEYS;

#pragma unroll
    for (int i = 0; i < 4; i++) {
        int flat = tid + i * 256;
        int j = flat >> 4, d4 = flat & 15;
        float4 v = *(const float4*)&bankbase[(size_t)j * CDIM + d4 * 4];
        if (!which) {
            ushort4 o;
            o.x = f2bf(v.x); o.y = f2bf(v.y); o.z = f2bf(v.z); o.w = f2bf(v.w);
            *(ushort4*)&outK[(size_t)(64 + j) * HD + d4 * 4] = o;
        } else {
            outV[(size_t)(d4 * 4 + 0) * LKEYS + 64 + j] = f2bf(v.x);
            outV[(size_t)(d4 * 4 + 1) * LKEYS + 64 + j] = f2bf(v.y);
            outV[(size_t)(d4 * 4 + 2) * LKEYS + 64 + j] = f2bf(v.z);
            outV[(size_t)(d4 * 4 + 3) * LKEYS + 64 + j] = f2bf(v.w);
        }
    }
    __syncthreads();

    int tx = tid & 15, ty = tid >> 4;
    float acc[4][4];
#pragma unroll
    for (int i = 0; i < 4; i++)
#pragma unroll
        for (int j = 0; j < 4; j++) acc[i][j] = 0.f;

#pragma unroll 4
    for (int s = 0; s < 128; s++) {
        float4 av = *(const float4*)&Es[s * 64 + ty * 4];
        float4 bv = *(const float4*)&Sl[s * 64 + tx * 4];
        float a[4] = {av.x, av.y, av.z, av.w};
        float bb[4] = {bv.x, bv.y, bv.z, bv.w};
#pragma unroll
        for (int i = 0; i < 4; i++)
#pragma unroll
            for (int j = 0; j < 4; j++)
                acc[i][j] += a[i] * bb[j];
    }
    if (!which) {
#pragma unroll
        for (int i = 0; i < 4; i++) {
            ushort4 o;
            o.x = f2bf(acc[i][0]); o.y = f2bf(acc[i][1]);
            o.z = f2bf(acc[i][2]); o.w = f2bf(acc[i][3]);
            *(ushort4*)&outK[(size_t)(ty * 4 + i) * HD + tx * 4] = o;
        }
    } else {
#pragma unroll
        for (int i = 0; i < 4; i++)
#pragma unroll
            for (int j = 0; j < 4; j++)
                outV[(size_t)(tx * 4 + j) * LKEYS + ty * 4 + i] = f2bf(acc[i][j]);
    }
}

// ---------------------------------------------------------------------------
// 4) MFMA attention (unchanged from R2)
// ---------------------------------------------------------------------------
__global__ __launch_bounds__(256) void attn_mfma_kernel(
    const ushort* __restrict__ qb, const ushort* __restrict__ kf,
    const ushort* __restrict__ vt, ushort* __restrict__ ob)
{
    __shared__ __align__(16) ushort lds[64 * 72 + 128 * 72 + 64 * 136];
    ushort* Qs = lds;
    ushort* Ks = lds + 64 * 72;
    ushort* Vs = lds + 64 * 72 + 128 * 72;
    ushort* Ps = lds;

    int tid  = threadIdx.x;
    int wave = tid >> 6, lane = tid & 63;
    int lm = lane & 15, lh = lane >> 4;
    int qt = blockIdx.x, h = blockIdx.y, b = blockIdx.z;

    const ushort* qbase = qb + ((size_t)(b * NSEQ + qt * 64)) * CDIM + h * HD;
    const ushort* kbase = kf + (size_t)(b * NH + h) * LKEYS * HD;
    const ushort* vbase = vt + (size_t)(b * NH + h) * HD * LKEYS;

#pragma unroll
    for (int it = 0; it < 2; it++) {
        int flat = tid + it * 256;
        int row = flat >> 3, seg = flat & 7;
        *(uint4*)&Qs[row * 72 + seg * 8] = *(const uint4*)&qbase[(size_t)row * CDIM + seg * 8];
    }
#pragma unroll
    for (int it = 0; it < 4; it++) {
        int flat = tid + it * 256;
        int row = flat >> 3, seg = flat & 7;
        *(uint4*)&Ks[row * 72 + seg * 8] = *(const uint4*)&kbase[(size_t)row * HD + seg * 8];
    }
#pragma unroll
    for (int it = 0; it < 4; it++) {
        int flat = tid + it * 256;
        int row = flat >> 4, seg = flat & 15;
        *(uint4*)&Vs[row * 136 + seg * 8] = *(const uint4*)&vbase[(size_t)row * LKEYS + seg * 8];
    }
    __syncthreads();

    f32x4 sacc[8] = {};
    bf16x8 aq[2];
#pragma unroll
    for (int ks = 0; ks < 2; ks++)
        aq[ks] = *(const bf16x8*)((const void*)&Qs[(wave * 16 + lm) * 72 + ks * 32 + lh * 8]);
#pragma unroll
    for (int j = 0; j < 8; j++)
#pragma unroll
        for (int ks = 0; ks < 2; ks++) {
            bf16x8 bk = *(const bf16x8*)((const void*)&Ks[(j * 16 + lm) * 72 + ks * 32 + lh * 8]);
            sacc[j] = __builtin_amdgcn_mfma_f32_16x16x32_bf16(aq[ks], bk, sacc[j], 0, 0, 0);
        }

    float rinv[4];
#pragma unroll
    for (int r = 0; r < 4; r++) {
        float m = sacc[0][r];
#pragma unroll
        for (int j = 1; j < 8; j++) m = fmaxf(m, sacc[j][r]);
#pragma unroll
        for (int off = 1; off < 16; off <<= 1) m = fmaxf(m, __shfl_xor(m, off, 64));
        float s = 0.f;
#pragma unroll
        for (int j = 0; j < 8; j++) {
            float e = __expf((sacc[j][r] - m) * 0.125f);
            sacc[j][r] = e;
            s += e;
        }
#pragma unroll
        for (int off = 1; off < 16; off <<= 1) s += __shfl_xor(s, off, 64);
        rinv[r] = 1.f / s;
    }

    __syncthreads();
#pragma unroll
    for (int j = 0; j < 8; j++)
#pragma unroll
        for (int r = 0; r < 4; r++)
            Ps[(size_t)(wave * 16 + lh * 4 + r) * 136 + j * 16 + lm] = f2bf(sacc[j][r] * rinv[r]);
    __syncthreads();

    f32x4 oacc[4] = {};
#pragma unroll
    for (int ks = 0; ks < 4; ks++) {
        bf16x8 ap = *(const bf16x8*)((const void*)&Ps[(wave * 16 + lm) * 136 + ks * 32 + lh * 8]);
#pragma unroll
        for (int j = 0; j < 4; j++) {
            bf16x8 bv = *(const bf16x8*)((const void*)&Vs[(j * 16 + lm) * 136 + ks * 32 + lh * 8]);
            oacc[j] = __builtin_amdgcn_mfma_f32_16x16x32_bf16(ap, bv, oacc[j], 0, 0, 0);
        }
    }

    ushort* obase = ob + ((size_t)(b * NSEQ + qt * 64)) * CDIM + h * HD;
#pragma unroll
    for (int j = 0; j < 4; j++)
#pragma unroll
        for (int r = 0; r < 4; r++)
            obase[(size_t)(wave * 16 + lh * 4 + r) * CDIM + j * 16 + lm] = f2bf(oacc[j][r]);
}

// ---------------------------------------------------------------------------
// launch
// ---------------------------------------------------------------------------
extern "C" void kernel_launch(void* const* d_in, const int* in_sizes, int n_in,
                              void* d_out, int out_size, void* d_ws, size_t ws_size,
                              hipStream_t stream)
{
    const float* x     = (const float*)d_in[0];
    const float* Wqkv  = (const float*)d_in[1];
    const float* bqkv  = (const float*)d_in[2];
    const float* Ek    = (const float*)d_in[3];
    const float* Ev    = (const float*)d_in[4];
    const float* Wproj = (const float*)d_in[5];
    const float* bproj = (const float*)d_in[6];
    const float* kbank = (const float*)d_in[7];
    const float* vbank = (const float*)d_in[8];
    float* out = (float*)d_out;
    float* ws  = (float*)d_ws;

    float*  kvp    = ws;                              //  6,291,456 f
    ushort* qb_bf  = (ushort*)ws;                     // alias kvp (time-disjoint)
    ushort* x_bf   = (ushort*)(ws + 12582912);
    ushort* aob    = x_bf;                            // alias (x_bf dead)
    ushort* xp_bf  = (ushort*)(ws + 25165824);
    ushort* Wq_t   = (ushort*)(ws + 26738688);        // 2304 x 768
    ushort* Wp_t   = (ushort*)(ws + 27623424);        // 768 x 768
    ushort* k_full = (ushort*)(ws + 27918336);
    ushort* v_fullT= (ushort*)(ws + 29491200);

    cvt_bf16_kernel<<<12288, 256, 0, stream>>>(x, x_bf, 3145728);
    transpose_cvt_kernel<<<dim3(72, 24), 256, 0, stream>>>(Wqkv, Wq_t, CDIM, 3 * CDIM);
    transpose_cvt_kernel<<<dim3(24, 24), 256, 0, stream>>>(Wproj, Wp_t, CDIM, CDIM);
    pool_kernel<<<1536, 256, 0, stream>>>(x, xp_bf);

    // KV projection: 4096 x 1536 (128^2 kernel — grid would be too small at 256^2)
    mfma_gemm_kernel<false><<<dim3(12, 32), 256, 0, stream>>>(
        xp_bf, Wq_t + (size_t)CDIM * CDIM, bqkv + CDIM, kvp, 4096, 2 * CDIM, CDIM);
    compress_kernel<<<dim3(NH, BB, 2), 256, 0, stream>>>(
        kvp, Ek, Ev, kbank, vbank, k_full, v_fullT);

    // Q projection: 32768 x 768, bf16 out — deep-pipelined 256^2 kernel
    gemm256_kernel<true><<<dim3(3, 128), 512, 0, stream>>>(
        x_bf, Wq_t, bqkv, qb_bf, BB * NSEQ, CDIM, CDIM);

    attn_mfma_kernel<<<dim3(16, NH, BB), 256, 0, stream>>>(qb_bf, k_full, v_fullT, aob);

    // output projection: 32768 x 768 fp32 out — deep-pipelined 256^2 kernel
    gemm256_kernel<false><<<dim3(3, 128), 512, 0, stream>>>(
        aob, Wp_t, bproj, out, BB * NSEQ, CDIM, CDIM);
}

// Round 4
// 405.449 us; speedup vs baseline: 1.0949x; 1.0949x over previous
//
#include <hip/hip_runtime.h>

#define BB    32
#define NSEQ  1024
#define CDIM  768
#define NH    12
#define HD    64
#define LKEYS 128
#define NPOOL 128

typedef __bf16 bf16x8 __attribute__((ext_vector_type(8)));
typedef float  f32x4  __attribute__((ext_vector_type(4)));

__device__ __forceinline__ ushort f2bf(float f) {
    union { float f; uint u; } v; v.f = f;
    uint u = v.u;
    uint r = u + 0x7FFFu + ((u >> 16) & 1u);   // RNE
    return (ushort)(r >> 16);
}
__device__ __forceinline__ uint pack2(float x, float y) {
    return (uint)f2bf(x) | ((uint)f2bf(y) << 16);
}

// ---------------------------------------------------------------------------
// 0a) fp32 -> bf16 bulk convert
// ---------------------------------------------------------------------------
__global__ __launch_bounds__(256) void cvt_bf16_kernel(const float* __restrict__ src,
                                                       ushort* __restrict__ dst, int n8)
{
    int idx = blockIdx.x * 256 + threadIdx.x;
    if (idx >= n8) return;
    float4 a = ((const float4*)src)[idx * 2];
    float4 b = ((const float4*)src)[idx * 2 + 1];
    uint4 o;
    o.x = pack2(a.x, a.y); o.y = pack2(a.z, a.w);
    o.z = pack2(b.x, b.y); o.w = pack2(b.z, b.w);
    ((uint4*)dst)[idx] = o;
}

// ---------------------------------------------------------------------------
// 0b) transpose + convert
// ---------------------------------------------------------------------------
__global__ __launch_bounds__(256) void transpose_cvt_kernel(const float* __restrict__ src,
                                                            ushort* __restrict__ dst,
                                                            int R, int C)
{
    __shared__ ushort tile[32][33];
    int bc = blockIdx.x * 32, br = blockIdx.y * 32;
    int tx = threadIdx.x & 31, ty = threadIdx.x >> 5;
#pragma unroll
    for (int i = 0; i < 32; i += 8)
        tile[ty + i][tx] = f2bf(src[(size_t)(br + ty + i) * C + bc + tx]);
    __syncthreads();
#pragma unroll
    for (int i = 0; i < 32; i += 8)
        dst[(size_t)(bc + ty + i) * R + br + tx] = tile[tx][ty + i];
}

// ---------------------------------------------------------------------------
// 1) pool
// ---------------------------------------------------------------------------
__global__ __launch_bounds__(256) void pool_kernel(const float* __restrict__ x,
                                                   ushort* __restrict__ xp)
{
    int idx = blockIdx.x * 256 + threadIdx.x;
    int c8 = idx % 96;
    int t  = idx / 96;
    int i  = t % NPOOL;
    int b  = t / NPOOL;
    if (b >= BB) return;
    const float4* x4 = (const float4*)x;
    size_t base0 = ((size_t)(b * NSEQ + 2 * i)) * 192 + c8 * 2;
    size_t base1 = base0 + 192;
    float4 a0 = x4[base0], a1 = x4[base0 + 1];
    float4 b0 = x4[base1], b1 = x4[base1 + 1];
    uint4 o;
    o.x = pack2(0.5f * (a0.x + b0.x), 0.5f * (a0.y + b0.y));
    o.y = pack2(0.5f * (a0.z + b0.z), 0.5f * (a0.w + b0.w));
    o.z = pack2(0.5f * (a1.x + b1.x), 0.5f * (a1.y + b1.y));
    o.w = pack2(0.5f * (a1.z + b1.z), 0.5f * (a1.w + b1.w));
    ((uint4*)xp)[idx] = o;
}

// ---------------------------------------------------------------------------
// 2a) 128^2-tile bf16 MFMA GEMM (m97 structure) — kept for KV proj
// ---------------------------------------------------------------------------
template <bool OBF16>
__global__ __launch_bounds__(256) void mfma_gemm_kernel(
    const ushort* __restrict__ A, const ushort* __restrict__ Bt,
    const float* __restrict__ bias, void* __restrict__ Cout,
    int M, int N, int K)
{
    __shared__ ushort As[128 * 32];
    __shared__ ushort Bs[128 * 32];

    int tid  = threadIdx.x;
    int wave = tid >> 6, lane = tid & 63;

    int nwg  = gridDim.x * gridDim.y;
    int bid  = blockIdx.y * gridDim.x + blockIdx.x;
    int q    = nwg >> 3, r = nwg & 7;
    int xcd  = bid & 7, j = bid >> 3;
    int flat = (xcd < r ? xcd * (q + 1) : r * (q + 1) + (xcd - r) * q) + j;
    int n0 = (flat % gridDim.x) * 128;
    int m0 = (flat / gridDim.x) * 128;

    int wm = wave >> 1, wn = wave & 1;
    int lm = lane & 15, lh = lane >> 4;

    f32x4 acc[4][4] = {};

    for (int k0 = 0; k0 < K; k0 += 32) {
        __syncthreads();
#pragma unroll
        for (int t = 0; t < 2; t++) {
            int fl = wave * 128 + t * 64 + lane;
            int row = fl >> 2, kc = (fl & 3) * 8;
            const ushort* gA = A  + (size_t)(m0 + row) * K + k0 + kc;
            const ushort* gB = Bt + (size_t)(n0 + row) * K + k0 + kc;
            __builtin_amdgcn_global_load_lds(
                (const __attribute__((address_space(1))) void*)gA,
                (__attribute__((address_space(3))) void*)(As + (size_t)(wave * 128 + t * 64) * 8),
                16, 0, 0);
            __builtin_amdgcn_global_load_lds(
                (const __attribute__((address_space(1))) void*)gB,
                (__attribute__((address_space(3))) void*)(Bs + (size_t)(wave * 128 + t * 64) * 8),
                16, 0, 0);
        }
        __syncthreads();

        bf16x8 af[4], bfr[4];
#pragma unroll
        for (int i = 0; i < 4; i++)
            af[i] = *(const bf16x8*)((const void*)&As[(wm * 64 + i * 16 + lm) * 32 + lh * 8]);
#pragma unroll
        for (int jj = 0; jj < 4; jj++)
            bfr[jj] = *(const bf16x8*)((const void*)&Bs[(wn * 64 + jj * 16 + lm) * 32 + lh * 8]);
#pragma unroll
        for (int i = 0; i < 4; i++)
#pragma unroll
            for (int jj = 0; jj < 4; jj++)
                acc[i][jj] = __builtin_amdgcn_mfma_f32_16x16x32_bf16(af[i], bfr[jj], acc[i][jj], 0, 0, 0);
    }

    int crow = m0 + wm * 64, ccol = n0 + wn * 64;
#pragma unroll
    for (int jj = 0; jj < 4; jj++) {
        int col = ccol + jj * 16 + lm;
        float bb = bias[col];
        if constexpr (OBF16) {
            ushort* C = (ushort*)Cout;
#pragma unroll
            for (int i = 0; i < 4; i++)
#pragma unroll
                for (int rr = 0; rr < 4; rr++)
                    C[(size_t)(crow + i * 16 + lh * 4 + rr) * N + col] = f2bf(acc[i][jj][rr] + bb);
        } else {
            float* C = (float*)Cout;
#pragma unroll
            for (int i = 0; i < 4; i++)
#pragma unroll
                for (int rr = 0; rr < 4; rr++)
                    C[(size_t)(crow + i * 16 + lh * 4 + rr) * N + col] = acc[i][jj][rr] + bb;
        }
    }
}

// ---------------------------------------------------------------------------
// 2b) 256x128-tile BK=64 pipelined GEMM (T1+T2+T4+T5 on the m97 base).
//    512 thr = 8 waves (4M x 2N), wave-out 64x64 (acc[4][4]), depth-3
//    circular LDS (3 x 48 KB = 144 KiB -> 1 block/CU), counted vmcnt
//    (12 steady / 6 / 0 tail), XOR swizzle chunk^= (row&7) on BOTH sides
//    (pre-swizzled global source, linear gload_lds dest; swizzled ds_read).
//    Grid for 32768x768: 6 x 128 = 768 blocks = exactly 3 rounds of 256 CUs.
//    Requires M%256==0, N%128==0, K%64==0.
// ---------------------------------------------------------------------------
template <bool OBF16>
__global__ __launch_bounds__(512) void gemm_bk64_kernel(
    const ushort* __restrict__ A, const ushort* __restrict__ Bt,
    const float* __restrict__ bias, void* __restrict__ Cout,
    int M, int N, int K)
{
    __shared__ ushort As[3][256 * 64];   // 3 x 32 KB
    __shared__ ushort Bs[3][128 * 64];   // 3 x 16 KB

    int tid  = threadIdx.x;
    int lane = tid & 63;
    int wave = tid >> 6;

    // XCD-aware bijective swizzle (T1), n-fastest flat (A-panel shared by
    // 6 consecutive flat ids -> L2 reuse within an XCD chunk)
    int nwg  = gridDim.x * gridDim.y;
    int bid  = blockIdx.y * gridDim.x + blockIdx.x;
    int q    = nwg >> 3, r = nwg & 7;
    int xcd  = bid & 7, jj0 = bid >> 3;
    int flat = (xcd < r ? xcd * (q + 1) : r * (q + 1) + (xcd - r) * q) + jj0;
    int n0 = (flat % gridDim.x) * 128;
    int m0 = (flat / gridDim.x) * 256;

    int wm = wave >> 1, wn = wave & 1;   // 4M x 2N
    int lm = lane & 15, lh = lane >> 4;

    int NT = K >> 6;                      // K-tiles of 64

    auto stage = [&](int tt) {
        int slot = tt - (tt / 3) * 3;     // tt % 3
        // A: 256 rows x 64k = 32 KB = 2048 x 16B chunks -> 4 loads/thread
#pragma unroll
        for (int ld = 0; ld < 4; ld++) {
            int fl = ld * 512 + tid;
            int prow = fl >> 3, pch = fl & 7;
            int lch  = pch ^ (prow & 7);
            const ushort* g = A + (size_t)(m0 + prow) * K + tt * 64 + lch * 8;
            __builtin_amdgcn_global_load_lds(
                (const __attribute__((address_space(1))) void*)g,
                (__attribute__((address_space(3))) void*)(&As[slot][fl * 8]),
                16, 0, 0);
        }
        // B: 128 rows x 64k = 16 KB = 1024 x 16B chunks -> 2 loads/thread
#pragma unroll
        for (int ld = 0; ld < 2; ld++) {
            int fl = ld * 512 + tid;
            int prow = fl >> 3, pch = fl & 7;
            int lch  = pch ^ (prow & 7);
            const ushort* g = Bt + (size_t)(n0 + prow) * K + tt * 64 + lch * 8;
            __builtin_amdgcn_global_load_lds(
                (const __attribute__((address_space(1))) void*)g,
                (__attribute__((address_space(3))) void*)(&Bs[slot][fl * 8]),
                16, 0, 0);
        }
    };

    f32x4 acc[4][4] = {};

    stage(0);
    stage(1);

    for (int t = 0; t < NT; t++) {
        int slot = t - (t / 3) * 3;

        if (t + 2 < NT) stage(t + 2);

        // counted vmcnt: 6 loads/tile, keep future tiles in flight
        if (t + 2 < NT)       asm volatile("s_waitcnt vmcnt(12)" ::: "memory");
        else if (t + 2 == NT) asm volatile("s_waitcnt vmcnt(6)"  ::: "memory");
        else                  asm volatile("s_waitcnt vmcnt(0)"  ::: "memory");
        __builtin_amdgcn_s_barrier();
        asm volatile("" ::: "memory");

        // B fragments for both k-halves (8 x ds_read_b128)
        bf16x8 bfr[2][4];
#pragma unroll
        for (int ks = 0; ks < 2; ks++)
#pragma unroll
            for (int jj = 0; jj < 4; jj++) {
                int rn = wn * 64 + jj * 16 + lm;
                int ch = (ks * 4 + lh) ^ (rn & 7);
                bfr[ks][jj] = *(const bf16x8*)((const void*)&Bs[slot][rn * 64 + ch * 8]);
            }
#pragma unroll
        for (int ks = 0; ks < 2; ks++) {
            bf16x8 af[4];
#pragma unroll
            for (int i = 0; i < 4; i++) {
                int rm = wm * 64 + i * 16 + lm;
                int ch = (ks * 4 + lh) ^ (rm & 7);
                af[i] = *(const bf16x8*)((const void*)&As[slot][rm * 64 + ch * 8]);
            }
            __builtin_amdgcn_s_setprio(1);
#pragma unroll
            for (int i = 0; i < 4; i++)
#pragma unroll
                for (int jj = 0; jj < 4; jj++)
                    acc[i][jj] = __builtin_amdgcn_mfma_f32_16x16x32_bf16(af[i], bfr[ks][jj], acc[i][jj], 0, 0, 0);
            __builtin_amdgcn_s_setprio(0);
        }
        __builtin_amdgcn_s_barrier();    // all reads of slot t done -> reusable
    }

    int crow = m0 + wm * 64, ccol = n0 + wn * 64;
#pragma unroll
    for (int jj = 0; jj < 4; jj++) {
        int col = ccol + jj * 16 + lm;
        float bb = bias[col];
        if constexpr (OBF16) {
            ushort* C = (ushort*)Cout;
#pragma unroll
            for (int i = 0; i < 4; i++)
#pragma unroll
                for (int rr = 0; rr < 4; rr++)
                    C[(size_t)(crow + i * 16 + lh * 4 + rr) * N + col] = f2bf(acc[i][jj][rr] + bb);
        } else {
            float* C = (float*)Cout;
#pragma unroll
            for (int i = 0; i < 4; i++)
#pragma unroll
                for (int rr = 0; rr < 4; rr++)
                    C[(size_t)(crow + i * 16 + lh * 4 + rr) * N + col] = acc[i][jj][rr] + bb;
        }
    }
}

// ---------------------------------------------------------------------------
// 3) compress + bank assembly -> bf16 outputs (k_full row-major, v_full^T)
// ---------------------------------------------------------------------------
__global__ __launch_bounds__(256) void compress_kernel(
    const float* __restrict__ kvp,
    const float* __restrict__ Ek, const float* __restrict__ Ev,
    const float* __restrict__ kbank, const float* __restrict__ vbank,
    ushort* __restrict__ kfull, ushort* __restrict__ vfullT)
{
    __shared__ float Es[128 * 64];
    __shared__ float Sl[128 * 64];

    int tid = threadIdx.x;
    int h = blockIdx.x, b = blockIdx.y, which = blockIdx.z;
    const float* E    = which ? Ev : Ek;
    const float* bank = which ? vbank : kbank;

#pragma unroll
    for (int i = 0; i < 8; i++) {
        int flat = tid + i * 256;
        *(float4*)&Es[flat * 4] = *(const float4*)&E[flat * 4];
    }
    const float* src = kvp + (size_t)b * 128 * 1536 + which * 768 + h * HD;
#pragma unroll
    for (int i = 0; i < 8; i++) {
        int flat = tid + i * 256;
        int s = flat >> 4, d4 = flat & 15;
        *(float4*)&Sl[s * 64 + d4 * 4] = *(const float4*)&src[(size_t)s * 1536 + d4 * 4];
    }

    const float* bankbase = bank + (size_t)b * 64 * CDIM + h * HD;
    ushort* outK = kfull  + (size_t)(b * NH + h) * LKEYS * HD;
    ushort* outV = vfullT + (size_t)(b * NH + h) * HD * LKEYS;

#pragma unroll
    for (int i = 0; i < 4; i++) {
        int flat = tid + i * 256;
        int j = flat >> 4, d4 = flat & 15;
        float4 v = *(const float4*)&bankbase[(size_t)j * CDIM + d4 * 4];
        if (!which) {
            ushort4 o;
            o.x = f2bf(v.x); o.y = f2bf(v.y); o.z = f2bf(v.z); o.w = f2bf(v.w);
            *(ushort4*)&outK[(size_t)(64 + j) * HD + d4 * 4] = o;
        } else {
            outV[(size_t)(d4 * 4 + 0) * LKEYS + 64 + j] = f2bf(v.x);
            outV[(size_t)(d4 * 4 + 1) * LKEYS + 64 + j] = f2bf(v.y);
            outV[(size_t)(d4 * 4 + 2) * LKEYS + 64 + j] = f2bf(v.z);
            outV[(size_t)(d4 * 4 + 3) * LKEYS + 64 + j] = f2bf(v.w);
        }
    }
    __syncthreads();

    int tx = tid & 15, ty = tid >> 4;
    float acc[4][4];
#pragma unroll
    for (int i = 0; i < 4; i++)
#pragma unroll
        for (int j = 0; j < 4; j++) acc[i][j] = 0.f;

#pragma unroll 4
    for (int s = 0; s < 128; s++) {
        float4 av = *(const float4*)&Es[s * 64 + ty * 4];
        float4 bv = *(const float4*)&Sl[s * 64 + tx * 4];
        float a[4] = {av.x, av.y, av.z, av.w};
        float bb[4] = {bv.x, bv.y, bv.z, bv.w};
#pragma unroll
        for (int i = 0; i < 4; i++)
#pragma unroll
            for (int j = 0; j < 4; j++)
                acc[i][j] += a[i] * bb[j];
    }
    if (!which) {
#pragma unroll
        for (int i = 0; i < 4; i++) {
            ushort4 o;
            o.x = f2bf(acc[i][0]); o.y = f2bf(acc[i][1]);
            o.z = f2bf(acc[i][2]); o.w = f2bf(acc[i][3]);
            *(ushort4*)&outK[(size_t)(ty * 4 + i) * HD + tx * 4] = o;
        }
    } else {
#pragma unroll
        for (int i = 0; i < 4; i++)
#pragma unroll
            for (int j = 0; j < 4; j++)
                outV[(size_t)(tx * 4 + j) * LKEYS + ty * 4 + i] = f2bf(acc[i][j]);
    }
}

// ---------------------------------------------------------------------------
// 4) MFMA attention (unchanged from R2)
// ---------------------------------------------------------------------------
__global__ __launch_bounds__(256) void attn_mfma_kernel(
    const ushort* __restrict__ qb, const ushort* __restrict__ kf,
    const ushort* __restrict__ vt, ushort* __restrict__ ob)
{
    __shared__ __align__(16) ushort lds[64 * 72 + 128 * 72 + 64 * 136];
    ushort* Qs = lds;
    ushort* Ks = lds + 64 * 72;
    ushort* Vs = lds + 64 * 72 + 128 * 72;
    ushort* Ps = lds;

    int tid  = threadIdx.x;
    int wave = tid >> 6, lane = tid & 63;
    int lm = lane & 15, lh = lane >> 4;
    int qt = blockIdx.x, h = blockIdx.y, b = blockIdx.z;

    const ushort* qbase = qb + ((size_t)(b * NSEQ + qt * 64)) * CDIM + h * HD;
    const ushort* kbase = kf + (size_t)(b * NH + h) * LKEYS * HD;
    const ushort* vbase = vt + (size_t)(b * NH + h) * HD * LKEYS;

#pragma unroll
    for (int it = 0; it < 2; it++) {
        int flat = tid + it * 256;
        int row = flat >> 3, seg = flat & 7;
        *(uint4*)&Qs[row * 72 + seg * 8] = *(const uint4*)&qbase[(size_t)row * CDIM + seg * 8];
    }
#pragma unroll
    for (int it = 0; it < 4; it++) {
        int flat = tid + it * 256;
        int row = flat >> 3, seg = flat & 7;
        *(uint4*)&Ks[row * 72 + seg * 8] = *(const uint4*)&kbase[(size_t)row * HD + seg * 8];
    }
#pragma unroll
    for (int it = 0; it < 4; it++) {
        int flat = tid + it * 256;
        int row = flat >> 4, seg = flat & 15;
        *(uint4*)&Vs[row * 136 + seg * 8] = *(const uint4*)&vbase[(size_t)row * LKEYS + seg * 8];
    }
    __syncthreads();

    f32x4 sacc[8] = {};
    bf16x8 aq[2];
#pragma unroll
    for (int ks = 0; ks < 2; ks++)
        aq[ks] = *(const bf16x8*)((const void*)&Qs[(wave * 16 + lm) * 72 + ks * 32 + lh * 8]);
#pragma unroll
    for (int j = 0; j < 8; j++)
#pragma unroll
        for (int ks = 0; ks < 2; ks++) {
            bf16x8 bk = *(const bf16x8*)((const void*)&Ks[(j * 16 + lm) * 72 + ks * 32 + lh * 8]);
            sacc[j] = __builtin_amdgcn_mfma_f32_16x16x32_bf16(aq[ks], bk, sacc[j], 0, 0, 0);
        }

    float rinv[4];
#pragma unroll
    for (int r = 0; r < 4; r++) {
        float m = sacc[0][r];
#pragma unroll
        for (int j = 1; j < 8; j++) m = fmaxf(m, sacc[j][r]);
#pragma unroll
        for (int off = 1; off < 16; off <<= 1) m = fmaxf(m, __shfl_xor(m, off, 64));
        float s = 0.f;
#pragma unroll
        for (int j = 0; j < 8; j++) {
            float e = __expf((sacc[j][r] - m) * 0.125f);
            sacc[j][r] = e;
            s += e;
        }
#pragma unroll
        for (int off = 1; off < 16; off <<= 1) s += __shfl_xor(s, off, 64);
        rinv[r] = 1.f / s;
    }

    __syncthreads();
#pragma unroll
    for (int j = 0; j < 8; j++)
#pragma unroll
        for (int r = 0; r < 4; r++)
            Ps[(size_t)(wave * 16 + lh * 4 + r) * 136 + j * 16 + lm] = f2bf(sacc[j][r] * rinv[r]);
    __syncthreads();

    f32x4 oacc[4] = {};
#pragma unroll
    for (int ks = 0; ks < 4; ks++) {
        bf16x8 ap = *(const bf16x8*)((const void*)&Ps[(wave * 16 + lm) * 136 + ks * 32 + lh * 8]);
#pragma unroll
        for (int j = 0; j < 4; j++) {
            bf16x8 bv = *(const bf16x8*)((const void*)&Vs[(j * 16 + lm) * 136 + ks * 32 + lh * 8]);
            oacc[j] = __builtin_amdgcn_mfma_f32_16x16x32_bf16(ap, bv, oacc[j], 0, 0, 0);
        }
    }

    ushort* obase = ob + ((size_t)(b * NSEQ + qt * 64)) * CDIM + h * HD;
#pragma unroll
    for (int j = 0; j < 4; j++)
#pragma unroll
        for (int r = 0; r < 4; r++)
            obase[(size_t)(wave * 16 + lh * 4 + r) * CDIM + j * 16 + lm] = f2bf(oacc[j][r]);
}

// ---------------------------------------------------------------------------
// launch
// ---------------------------------------------------------------------------
extern "C" void kernel_launch(void* const* d_in, const int* in_sizes, int n_in,
                              void* d_out, int out_size, void* d_ws, size_t ws_size,
                              hipStream_t stream)
{
    const float* x     = (const float*)d_in[0];
    const float* Wqkv  = (const float*)d_in[1];
    const float* bqkv  = (const float*)d_in[2];
    const float* Ek    = (const float*)d_in[3];
    const float* Ev    = (const float*)d_in[4];
    const float* Wproj = (const float*)d_in[5];
    const float* bproj = (const float*)d_in[6];
    const float* kbank = (const float*)d_in[7];
    const float* vbank = (const float*)d_in[8];
    float* out = (float*)d_out;
    float* ws  = (float*)d_ws;

    float*  kvp    = ws;                              //  6,291,456 f
    ushort* qb_bf  = (ushort*)ws;                     // alias kvp (time-disjoint)
    ushort* x_bf   = (ushort*)(ws + 12582912);
    ushort* aob    = x_bf;                            // alias (x_bf dead)
    ushort* xp_bf  = (ushort*)(ws + 25165824);
    ushort* Wq_t   = (ushort*)(ws + 26738688);        // 2304 x 768
    ushort* Wp_t   = (ushort*)(ws + 27623424);        // 768 x 768
    ushort* k_full = (ushort*)(ws + 27918336);
    ushort* v_fullT= (ushort*)(ws + 29491200);

    cvt_bf16_kernel<<<12288, 256, 0, stream>>>(x, x_bf, 3145728);
    transpose_cvt_kernel<<<dim3(72, 24), 256, 0, stream>>>(Wqkv, Wq_t, CDIM, 3 * CDIM);
    transpose_cvt_kernel<<<dim3(24, 24), 256, 0, stream>>>(Wproj, Wp_t, CDIM, CDIM);
    pool_kernel<<<1536, 256, 0, stream>>>(x, xp_bf);

    // KV projection: 4096 x 1536 (128^2 kernel — small grid)
    mfma_gemm_kernel<false><<<dim3(12, 32), 256, 0, stream>>>(
        xp_bf, Wq_t + (size_t)CDIM * CDIM, bqkv + CDIM, kvp, 4096, 2 * CDIM, CDIM);
    compress_kernel<<<dim3(NH, BB, 2), 256, 0, stream>>>(
        kvp, Ek, Ev, kbank, vbank, k_full, v_fullT);

    // Q projection: 32768 x 768, bf16 out — 256x128 BK=64 pipelined kernel
    gemm_bk64_kernel<true><<<dim3(6, 128), 512, 0, stream>>>(
        x_bf, Wq_t, bqkv, qb_bf, BB * NSEQ, CDIM, CDIM);

    attn_mfma_kernel<<<dim3(16, NH, BB), 256, 0, stream>>>(qb_bf, k_full, v_fullT, aob);

    // output projection: 32768 x 768 fp32 out — 256x128 BK=64 pipelined kernel
    gemm_bk64_kernel<false><<<dim3(6, 128), 512, 0, stream>>>(
        aob, Wp_t, bproj, out, BB * NSEQ, CDIM, CDIM);
}

// Round 5
// 388.887 us; speedup vs baseline: 1.1415x; 1.0426x over previous
//
#include <hip/hip_runtime.h>

#define BB    32
#define NSEQ  1024
#define CDIM  768
#define NH    12
#define HD    64
#define LKEYS 128
#define NPOOL 128

typedef __bf16 bf16x8 __attribute__((ext_vector_type(8)));
typedef float  f32x4  __attribute__((ext_vector_type(4)));

__device__ __forceinline__ ushort f2bf(float f) {
    union { float f; uint u; } v; v.f = f;
    uint u = v.u;
    uint r = u + 0x7FFFu + ((u >> 16) & 1u);   // RNE
    return (ushort)(r >> 16);
}
__device__ __forceinline__ uint pack2(float x, float y) {
    return (uint)f2bf(x) | ((uint)f2bf(y) << 16);
}

// ---------------------------------------------------------------------------
// 0) merged transpose+convert for both weights: dst[c*R + r] = bf16(src[r*C+c])
//    z=0: Wqkv (768 x 2304), z=1: Wproj (768 x 768)
// ---------------------------------------------------------------------------
__global__ __launch_bounds__(256) void transpose2_cvt_kernel(
    const float* __restrict__ A0, ushort* __restrict__ D0,
    const float* __restrict__ A1, ushort* __restrict__ D1)
{
    __shared__ ushort tile[32][33];
    int z = blockIdx.z;
    if (z == 1 && blockIdx.x >= 24) return;
    const float* src = z ? A1 : A0;
    ushort* dst      = z ? D1 : D0;
    int C = z ? CDIM : 3 * CDIM;
    const int R = CDIM;

    int bc = blockIdx.x * 32, br = blockIdx.y * 32;
    int tx = threadIdx.x & 31, ty = threadIdx.x >> 5;
#pragma unroll
    for (int i = 0; i < 32; i += 8)
        tile[ty + i][tx] = f2bf(src[(size_t)(br + ty + i) * C + bc + tx]);
    __syncthreads();
#pragma unroll
    for (int i = 0; i < 32; i += 8)
        dst[(size_t)(bc + ty + i) * R + br + tx] = tile[tx][ty + i];
}

// ---------------------------------------------------------------------------
// 1) pool: xp[b,i,c] = 0.5*(x[b,2i,c]+x[b,2i+1,c]) -> bf16, i < 128
// ---------------------------------------------------------------------------
__global__ __launch_bounds__(256) void pool_kernel(const float* __restrict__ x,
                                                   ushort* __restrict__ xp)
{
    int idx = blockIdx.x * 256 + threadIdx.x;
    int c8 = idx % 96;
    int t  = idx / 96;
    int i  = t % NPOOL;
    int b  = t / NPOOL;
    if (b >= BB) return;
    const float4* x4 = (const float4*)x;
    size_t base0 = ((size_t)(b * NSEQ + 2 * i)) * 192 + c8 * 2;
    size_t base1 = base0 + 192;
    float4 a0 = x4[base0], a1 = x4[base0 + 1];
    float4 b0 = x4[base1], b1 = x4[base1 + 1];
    uint4 o;
    o.x = pack2(0.5f * (a0.x + b0.x), 0.5f * (a0.y + b0.y));
    o.y = pack2(0.5f * (a0.z + b0.z), 0.5f * (a0.w + b0.w));
    o.z = pack2(0.5f * (a1.x + b1.x), 0.5f * (a1.y + b1.y));
    o.w = pack2(0.5f * (a1.z + b1.z), 0.5f * (a1.w + b1.w));
    ((uint4*)xp)[idx] = o;
}

// ---------------------------------------------------------------------------
// 2a) 128^2-tile bf16 MFMA GEMM (m97 structure) — kept for KV proj
// ---------------------------------------------------------------------------
template <bool OBF16>
__global__ __launch_bounds__(256) void mfma_gemm_kernel(
    const ushort* __restrict__ A, const ushort* __restrict__ Bt,
    const float* __restrict__ bias, void* __restrict__ Cout,
    int M, int N, int K)
{
    __shared__ ushort As[128 * 32];
    __shared__ ushort Bs[128 * 32];

    int tid  = threadIdx.x;
    int wave = tid >> 6, lane = tid & 63;

    int nwg  = gridDim.x * gridDim.y;
    int bid  = blockIdx.y * gridDim.x + blockIdx.x;
    int q    = nwg >> 3, r = nwg & 7;
    int xcd  = bid & 7, j = bid >> 3;
    int flat = (xcd < r ? xcd * (q + 1) : r * (q + 1) + (xcd - r) * q) + j;
    int n0 = (flat % gridDim.x) * 128;
    int m0 = (flat / gridDim.x) * 128;

    int wm = wave >> 1, wn = wave & 1;
    int lm = lane & 15, lh = lane >> 4;

    f32x4 acc[4][4] = {};

    for (int k0 = 0; k0 < K; k0 += 32) {
        __syncthreads();
#pragma unroll
        for (int t = 0; t < 2; t++) {
            int fl = wave * 128 + t * 64 + lane;
            int row = fl >> 2, kc = (fl & 3) * 8;
            const ushort* gA = A  + (size_t)(m0 + row) * K + k0 + kc;
            const ushort* gB = Bt + (size_t)(n0 + row) * K + k0 + kc;
            __builtin_amdgcn_global_load_lds(
                (const __attribute__((address_space(1))) void*)gA,
                (__attribute__((address_space(3))) void*)(As + (size_t)(wave * 128 + t * 64) * 8),
                16, 0, 0);
            __builtin_amdgcn_global_load_lds(
                (const __attribute__((address_space(1))) void*)gB,
                (__attribute__((address_space(3))) void*)(Bs + (size_t)(wave * 128 + t * 64) * 8),
                16, 0, 0);
        }
        __syncthreads();

        bf16x8 af[4], bfr[4];
#pragma unroll
        for (int i = 0; i < 4; i++)
            af[i] = *(const bf16x8*)((const void*)&As[(wm * 64 + i * 16 + lm) * 32 + lh * 8]);
#pragma unroll
        for (int jj = 0; jj < 4; jj++)
            bfr[jj] = *(const bf16x8*)((const void*)&Bs[(wn * 64 + jj * 16 + lm) * 32 + lh * 8]);
#pragma unroll
        for (int i = 0; i < 4; i++)
#pragma unroll
            for (int jj = 0; jj < 4; jj++)
                acc[i][jj] = __builtin_amdgcn_mfma_f32_16x16x32_bf16(af[i], bfr[jj], acc[i][jj], 0, 0, 0);
    }

    int crow = m0 + wm * 64, ccol = n0 + wn * 64;
#pragma unroll
    for (int jj = 0; jj < 4; jj++) {
        int col = ccol + jj * 16 + lm;
        float bb = bias[col];
        if constexpr (OBF16) {
            ushort* C = (ushort*)Cout;
#pragma unroll
            for (int i = 0; i < 4; i++)
#pragma unroll
                for (int rr = 0; rr < 4; rr++)
                    C[(size_t)(crow + i * 16 + lh * 4 + rr) * N + col] = f2bf(acc[i][jj][rr] + bb);
        } else {
            float* C = (float*)Cout;
#pragma unroll
            for (int i = 0; i < 4; i++)
#pragma unroll
                for (int rr = 0; rr < 4; rr++)
                    C[(size_t)(crow + i * 16 + lh * 4 + rr) * N + col] = acc[i][jj][rr] + bb;
        }
    }
}

// ---------------------------------------------------------------------------
// 2b) 128x128-tile BK=64 double-buffered GEMM, 256 thr = 4 waves (2x2),
//    wave-out 64x64 (acc[4][4]), 64 KB LDS -> 2 blocks/CU, counted vmcnt,
//    XOR swizzle (both-sides), setprio around MFMA.
//    AFP32: A is fp32, reg-staged with in-flight fp32->bf16 convert (fuses
//    the old cvt kernel into the GEMM). Otherwise A is bf16 via gload_lds.
//    Requires M%128==0, N%128==0, K%64==0, K/64 even (for AFP32 path).
// ---------------------------------------------------------------------------
template <bool AFP32, bool OBF16>
__global__ __launch_bounds__(256) void gemm_db_kernel(
    const void* __restrict__ Ain, const ushort* __restrict__ Bt,
    const float* __restrict__ bias, void* __restrict__ Cout,
    int M, int N, int K)
{
    __shared__ ushort As[2][128 * 64];   // 2 x 16 KB
    __shared__ ushort Bs[2][128 * 64];   // 2 x 16 KB

    int tid  = threadIdx.x;
    int lane = tid & 63;
    int wave = tid >> 6;

    int nwg  = gridDim.x * gridDim.y;
    int bid  = blockIdx.y * gridDim.x + blockIdx.x;
    int q    = nwg >> 3, r = nwg & 7;
    int xcd  = bid & 7, jj0 = bid >> 3;
    int flat = (xcd < r ? xcd * (q + 1) : r * (q + 1) + (xcd - r) * q) + jj0;
    int n0 = (flat % gridDim.x) * 128;
    int m0 = (flat / gridDim.x) * 128;

    int wm = wave >> 1, wn = wave & 1;
    int lm = lane & 15, lh = lane >> 4;

    const int NT = K >> 6;

    // B staging: 128 rows x 64 k bf16 = 16 KB = 1024 chunks -> 4 gloads/thread
    auto stageB = [&](int tt) {
        int slot = tt & 1;
#pragma unroll
        for (int ld = 0; ld < 4; ld++) {
            int c = ld * 256 + tid;
            int prow = c >> 3, pch = c & 7;
            int lch = pch ^ (prow & 7);
            const ushort* g = Bt + (size_t)(n0 + prow) * K + tt * 64 + lch * 8;
            __builtin_amdgcn_global_load_lds(
                (const __attribute__((address_space(1))) void*)g,
                (__attribute__((address_space(3))) void*)(&Bs[slot][c * 8]),
                16, 0, 0);
        }
    };
    // A staging (bf16 path): same pattern
    auto stageA16 = [&](int tt) {
        const ushort* A = (const ushort*)Ain;
        int slot = tt & 1;
#pragma unroll
        for (int ld = 0; ld < 4; ld++) {
            int c = ld * 256 + tid;
            int prow = c >> 3, pch = c & 7;
            int lch = pch ^ (prow & 7);
            const ushort* g = A + (size_t)(m0 + prow) * K + tt * 64 + lch * 8;
            __builtin_amdgcn_global_load_lds(
                (const __attribute__((address_space(1))) void*)g,
                (__attribute__((address_space(3))) void*)(&As[slot][c * 8]),
                16, 0, 0);
        }
    };
    // A staging (fp32 path): issue 8 float4 loads / thread into regs
    auto loadA32 = [&](int tt, float4* ap) {
        const float* A = (const float*)Ain;
#pragma unroll
        for (int ld = 0; ld < 4; ld++) {
            int c = ld * 256 + tid;
            int prow = c >> 3, pch = c & 7;
            const float* g = A + (size_t)(m0 + prow) * K + tt * 64 + pch * 8;
            ap[ld * 2]     = *(const float4*)g;
            ap[ld * 2 + 1] = *(const float4*)(g + 4);
        }
    };
    auto writeA32 = [&](int tt, const float4* ap) {
        int slot = tt & 1;
#pragma unroll
        for (int ld = 0; ld < 4; ld++) {
            int c = ld * 256 + tid;
            int prow = c >> 3, pch = c & 7;
            uint4 o;
            o.x = pack2(ap[ld * 2].x,     ap[ld * 2].y);
            o.y = pack2(ap[ld * 2].z,     ap[ld * 2].w);
            o.z = pack2(ap[ld * 2 + 1].x, ap[ld * 2 + 1].y);
            o.w = pack2(ap[ld * 2 + 1].z, ap[ld * 2 + 1].w);
            *(uint4*)&As[slot][prow * 64 + ((pch ^ (prow & 7)) * 8)] = o;
        }
    };

    f32x4 acc[4][4] = {};

    auto compute = [&](int slot) {
        bf16x8 bfr[4], af[4];
#pragma unroll
        for (int ks = 0; ks < 2; ks++) {
#pragma unroll
            for (int jj = 0; jj < 4; jj++) {
                int rn = wn * 64 + jj * 16 + lm;
                int ch = (ks * 4 + lh) ^ (rn & 7);
                bfr[jj] = *(const bf16x8*)((const void*)&Bs[slot][rn * 64 + ch * 8]);
            }
#pragma unroll
            for (int i = 0; i < 4; i++) {
                int rm = wm * 64 + i * 16 + lm;
                int ch = (ks * 4 + lh) ^ (rm & 7);
                af[i] = *(const bf16x8*)((const void*)&As[slot][rm * 64 + ch * 8]);
            }
            __builtin_amdgcn_s_setprio(1);
#pragma unroll
            for (int i = 0; i < 4; i++)
#pragma unroll
                for (int jj = 0; jj < 4; jj++)
                    acc[i][jj] = __builtin_amdgcn_mfma_f32_16x16x32_bf16(af[i], bfr[jj], acc[i][jj], 0, 0, 0);
            __builtin_amdgcn_s_setprio(0);
        }
    };

    if constexpr (AFP32) {
        float4 apre0[8], apre1[8];
        // prologue: A(0) regs; B(0), B(1) in flight
        loadA32(0, apre0);
        stageB(0);
        stageB(1);
        // iteration body; invariant at entry: A(t) loads + B(t) + B(t+1) issued,
        // outstanding = A(t)8 + B(t)4 + B(t+1)4 (newest = B(t+1)).
        auto iter = [&](int t, float4* cur, float4* nxt) {
            int slot = t & 1;
            if (t + 1 < NT) asm volatile("s_waitcnt vmcnt(4)" ::: "memory");
            else            asm volatile("s_waitcnt vmcnt(0)" ::: "memory");
            writeA32(t, cur);                       // cvt + swizzled ds_write
            if (t + 1 < NT) loadA32(t + 1, nxt);    // issue next A loads
            asm volatile("s_waitcnt lgkmcnt(0)" ::: "memory");
            __builtin_amdgcn_s_barrier();           // publish As/Bs[slot]
            asm volatile("" ::: "memory");
            compute(slot);
            __builtin_amdgcn_s_barrier();           // retire reads of [slot]
            asm volatile("" ::: "memory");
            if (t + 2 < NT) stageB(t + 2);          // into Bs[slot] (now free)
        };
        for (int t = 0; t < NT; t += 2) {
            iter(t,     apre0, apre1);
            iter(t + 1, apre1, apre0);
        }
    } else {
        stageA16(0); stageB(0);
        stageA16(1); stageB(1);
        for (int t = 0; t < NT; t++) {
            int slot = t & 1;
            if (t + 1 < NT) asm volatile("s_waitcnt vmcnt(8)" ::: "memory");
            else            asm volatile("s_waitcnt vmcnt(0)" ::: "memory");
            __builtin_amdgcn_s_barrier();           // tile t resident everywhere
            asm volatile("" ::: "memory");
            compute(slot);
            __builtin_amdgcn_s_barrier();           // reads of [slot] retired
            asm volatile("" ::: "memory");
            if (t + 2 < NT) { stageA16(t + 2); stageB(t + 2); }
        }
    }

    int crow = m0 + wm * 64, ccol = n0 + wn * 64;
#pragma unroll
    for (int jj = 0; jj < 4; jj++) {
        int col = ccol + jj * 16 + lm;
        float bb = bias[col];
        if constexpr (OBF16) {
            ushort* C = (ushort*)Cout;
#pragma unroll
            for (int i = 0; i < 4; i++)
#pragma unroll
                for (int rr = 0; rr < 4; rr++)
                    C[(size_t)(crow + i * 16 + lh * 4 + rr) * N + col] = f2bf(acc[i][jj][rr] + bb);
        } else {
            float* C = (float*)Cout;
#pragma unroll
            for (int i = 0; i < 4; i++)
#pragma unroll
                for (int rr = 0; rr < 4; rr++)
                    C[(size_t)(crow + i * 16 + lh * 4 + rr) * N + col] = acc[i][jj][rr] + bb;
        }
    }
}

// ---------------------------------------------------------------------------
// 3) compress + bank assembly -> bf16 outputs (k_full row-major, v_full^T)
// ---------------------------------------------------------------------------
__global__ __launch_bounds__(256) void compress_kernel(
    const float* __restrict__ kvp,
    const float* __restrict__ Ek, const float* __restrict__ Ev,
    const float* __restrict__ kbank, const float* __restrict__ vbank,
    ushort* __restrict__ kfull, ushort* __restrict__ vfullT)
{
    __shared__ float Es[128 * 64];
    __shared__ float Sl[128 * 64];

    int tid = threadIdx.x;
    int h = blockIdx.x, b = blockIdx.y, which = blockIdx.z;
    const float* E    = which ? Ev : Ek;
    const float* bank = which ? vbank : kbank;

#pragma unroll
    for (int i = 0; i < 8; i++) {
        int flat = tid + i * 256;
        *(float4*)&Es[flat * 4] = *(const float4*)&E[flat * 4];
    }
    const float* src = kvp + (size_t)b * 128 * 1536 + which * 768 + h * HD;
#pragma unroll
    for (int i = 0; i < 8; i++) {
        int flat = tid + i * 256;
        int s = flat >> 4, d4 = flat & 15;
        *(float4*)&Sl[s * 64 + d4 * 4] = *(const float4*)&src[(size_t)s * 1536 + d4 * 4];
    }

    const float* bankbase = bank + (size_t)b * 64 * CDIM + h * HD;
    ushort* outK = kfull  + (size_t)(b * NH + h) * LKEYS * HD;
    ushort* outV = vfullT + (size_t)(b * NH + h) * HD * LKEYS;

#pragma unroll
    for (int i = 0; i < 4; i++) {
        int flat = tid + i * 256;
        int j = flat >> 4, d4 = flat & 15;
        float4 v = *(const float4*)&bankbase[(size_t)j * CDIM + d4 * 4];
        if (!which) {
            ushort4 o;
            o.x = f2bf(v.x); o.y = f2bf(v.y); o.z = f2bf(v.z); o.w = f2bf(v.w);
            *(ushort4*)&outK[(size_t)(64 + j) * HD + d4 * 4] = o;
        } else {
            outV[(size_t)(d4 * 4 + 0) * LKEYS + 64 + j] = f2bf(v.x);
            outV[(size_t)(d4 * 4 + 1) * LKEYS + 64 + j] = f2bf(v.y);
            outV[(size_t)(d4 * 4 + 2) * LKEYS + 64 + j] = f2bf(v.z);
            outV[(size_t)(d4 * 4 + 3) * LKEYS + 64 + j] = f2bf(v.w);
        }
    }
    __syncthreads();

    int tx = tid & 15, ty = tid >> 4;
    float acc[4][4];
#pragma unroll
    for (int i = 0; i < 4; i++)
#pragma unroll
        for (int j = 0; j < 4; j++) acc[i][j] = 0.f;

#pragma unroll 4
    for (int s = 0; s < 128; s++) {
        float4 av = *(const float4*)&Es[s * 64 + ty * 4];
        float4 bv = *(const float4*)&Sl[s * 64 + tx * 4];
        float a[4] = {av.x, av.y, av.z, av.w};
        float bb[4] = {bv.x, bv.y, bv.z, bv.w};
#pragma unroll
        for (int i = 0; i < 4; i++)
#pragma unroll
            for (int j = 0; j < 4; j++)
                acc[i][j] += a[i] * bb[j];
    }
    if (!which) {
#pragma unroll
        for (int i = 0; i < 4; i++) {
            ushort4 o;
            o.x = f2bf(acc[i][0]); o.y = f2bf(acc[i][1]);
            o.z = f2bf(acc[i][2]); o.w = f2bf(acc[i][3]);
            *(ushort4*)&outK[(size_t)(ty * 4 + i) * HD + tx * 4] = o;
        }
    } else {
#pragma unroll
        for (int i = 0; i < 4; i++)
#pragma unroll
            for (int j = 0; j < 4; j++)
                outV[(size_t)(tx * 4 + j) * LKEYS + ty * 4 + i] = f2bf(acc[i][j]);
    }
}

// ---------------------------------------------------------------------------
// 4) MFMA attention (unchanged)
// ---------------------------------------------------------------------------
__global__ __launch_bounds__(256) void attn_mfma_kernel(
    const ushort* __restrict__ qb, const ushort* __restrict__ kf,
    const ushort* __restrict__ vt, ushort* __restrict__ ob)
{
    __shared__ __align__(16) ushort lds[64 * 72 + 128 * 72 + 64 * 136];
    ushort* Qs = lds;
    ushort* Ks = lds + 64 * 72;
    ushort* Vs = lds + 64 * 72 + 128 * 72;
    ushort* Ps = lds;

    int tid  = threadIdx.x;
    int wave = tid >> 6, lane = tid & 63;
    int lm = lane & 15, lh = lane >> 4;
    int qt = blockIdx.x, h = blockIdx.y, b = blockIdx.z;

    const ushort* qbase = qb + ((size_t)(b * NSEQ + qt * 64)) * CDIM + h * HD;
    const ushort* kbase = kf + (size_t)(b * NH + h) * LKEYS * HD;
    const ushort* vbase = vt + (size_t)(b * NH + h) * HD * LKEYS;

#pragma unroll
    for (int it = 0; it < 2; it++) {
        int flat = tid + it * 256;
        int row = flat >> 3, seg = flat & 7;
        *(uint4*)&Qs[row * 72 + seg * 8] = *(const uint4*)&qbase[(size_t)row * CDIM + seg * 8];
    }
#pragma unroll
    for (int it = 0; it < 4; it++) {
        int flat = tid + it * 256;
        int row = flat >> 3, seg = flat & 7;
        *(uint4*)&Ks[row * 72 + seg * 8] = *(const uint4*)&kbase[(size_t)row * HD + seg * 8];
    }
#pragma unroll
    for (int it = 0; it < 4; it++) {
        int flat = tid + it * 256;
        int row = flat >> 4, seg = flat & 15;
        *(uint4*)&Vs[row * 136 + seg * 8] = *(const uint4*)&vbase[(size_t)row * LKEYS + seg * 8];
    }
    __syncthreads();

    f32x4 sacc[8] = {};
    bf16x8 aq[2];
#pragma unroll
    for (int ks = 0; ks < 2; ks++)
        aq[ks] = *(const bf16x8*)((const void*)&Qs[(wave * 16 + lm) * 72 + ks * 32 + lh * 8]);
#pragma unroll
    for (int j = 0; j < 8; j++)
#pragma unroll
        for (int ks = 0; ks < 2; ks++) {
            bf16x8 bk = *(const bf16x8*)((const void*)&Ks[(j * 16 + lm) * 72 + ks * 32 + lh * 8]);
            sacc[j] = __builtin_amdgcn_mfma_f32_16x16x32_bf16(aq[ks], bk, sacc[j], 0, 0, 0);
        }

    float rinv[4];
#pragma unroll
    for (int r = 0; r < 4; r++) {
        float m = sacc[0][r];
#pragma unroll
        for (int j = 1; j < 8; j++) m = fmaxf(m, sacc[j][r]);
#pragma unroll
        for (int off = 1; off < 16; off <<= 1) m = fmaxf(m, __shfl_xor(m, off, 64));
        float s = 0.f;
#pragma unroll
        for (int j = 0; j < 8; j++) {
            float e = __expf((sacc[j][r] - m) * 0.125f);
            sacc[j][r] = e;
            s += e;
        }
#pragma unroll
        for (int off = 1; off < 16; off <<= 1) s += __shfl_xor(s, off, 64);
        rinv[r] = 1.f / s;
    }

    __syncthreads();
#pragma unroll
    for (int j = 0; j < 8; j++)
#pragma unroll
        for (int r = 0; r < 4; r++)
            Ps[(size_t)(wave * 16 + lh * 4 + r) * 136 + j * 16 + lm] = f2bf(sacc[j][r] * rinv[r]);
    __syncthreads();

    f32x4 oacc[4] = {};
#pragma unroll
    for (int ks = 0; ks < 4; ks++) {
        bf16x8 ap = *(const bf16x8*)((const void*)&Ps[(wave * 16 + lm) * 136 + ks * 32 + lh * 8]);
#pragma unroll
        for (int j = 0; j < 4; j++) {
            bf16x8 bv = *(const bf16x8*)((const void*)&Vs[(j * 16 + lm) * 136 + ks * 32 + lh * 8]);
            oacc[j] = __builtin_amdgcn_mfma_f32_16x16x32_bf16(ap, bv, oacc[j], 0, 0, 0);
        }
    }

    ushort* obase = ob + ((size_t)(b * NSEQ + qt * 64)) * CDIM + h * HD;
#pragma unroll
    for (int j = 0; j < 4; j++)
#pragma unroll
        for (int r = 0; r < 4; r++)
            obase[(size_t)(wave * 16 + lh * 4 + r) * CDIM + j * 16 + lm] = f2bf(oacc[j][r]);
}

// ---------------------------------------------------------------------------
// launch
// ---------------------------------------------------------------------------
extern "C" void kernel_launch(void* const* d_in, const int* in_sizes, int n_in,
                              void* d_out, int out_size, void* d_ws, size_t ws_size,
                              hipStream_t stream)
{
    const float* x     = (const float*)d_in[0];
    const float* Wqkv  = (const float*)d_in[1];
    const float* bqkv  = (const float*)d_in[2];
    const float* Ek    = (const float*)d_in[3];
    const float* Ev    = (const float*)d_in[4];
    const float* Wproj = (const float*)d_in[5];
    const float* bproj = (const float*)d_in[6];
    const float* kbank = (const float*)d_in[7];
    const float* vbank = (const float*)d_in[8];
    float* out = (float*)d_out;
    float* ws  = (float*)d_ws;

    float*  kvp    = ws;                              //  6,291,456 f
    ushort* qb_bf  = (ushort*)ws;                     // alias kvp (time-disjoint)
    ushort* aob    = (ushort*)(ws + 12582912);        // 25,165,824 us
    ushort* xp_bf  = (ushort*)(ws + 25165824);
    ushort* Wq_t   = (ushort*)(ws + 26738688);        // 2304 x 768
    ushort* Wp_t   = (ushort*)(ws + 27623424);        // 768 x 768
    ushort* k_full = (ushort*)(ws + 27918336);
    ushort* v_fullT= (ushort*)(ws + 29491200);

    transpose2_cvt_kernel<<<dim3(72, 24, 2), 256, 0, stream>>>(Wqkv, Wq_t, Wproj, Wp_t);
    pool_kernel<<<1536, 256, 0, stream>>>(x, xp_bf);

    // KV projection: 4096 x 1536 (m97 kernel — small grid)
    mfma_gemm_kernel<false><<<dim3(12, 32), 256, 0, stream>>>(
        xp_bf, Wq_t + (size_t)CDIM * CDIM, bqkv + CDIM, kvp, 4096, 2 * CDIM, CDIM);
    compress_kernel<<<dim3(NH, BB, 2), 256, 0, stream>>>(
        kvp, Ek, Ev, kbank, vbank, k_full, v_fullT);

    // Q projection: 32768 x 768, fused fp32->bf16 A staging, bf16 out
    gemm_db_kernel<true, true><<<dim3(6, 256), 256, 0, stream>>>(
        x, Wq_t, bqkv, qb_bf, BB * NSEQ, CDIM, CDIM);

    attn_mfma_kernel<<<dim3(16, NH, BB), 256, 0, stream>>>(qb_bf, k_full, v_fullT, aob);

    // output projection: bf16 A via gload_lds, fp32 out
    gemm_db_kernel<false, false><<<dim3(6, 256), 256, 0, stream>>>(
        aob, Wp_t, bproj, out, BB * NSEQ, CDIM, CDIM);
}

// Round 7
// 374.452 us; speedup vs baseline: 1.1855x; 1.0385x over previous
//
#include <hip/hip_runtime.h>

#define BB    32
#define NSEQ  1024
#define CDIM  768
#define NH    12
#define HD    64
#define LKEYS 128
#define NPOOL 128

typedef __bf16 bf16x8 __attribute__((ext_vector_type(8)));
typedef float  f32x4  __attribute__((ext_vector_type(4)));

__device__ __forceinline__ ushort f2bf(float f) {
    union { float f; uint u; } v; v.f = f;
    uint u = v.u;
    uint r = u + 0x7FFFu + ((u >> 16) & 1u);   // RNE
    return (ushort)(r >> 16);
}
__device__ __forceinline__ uint pack2(float x, float y) {
    return (uint)f2bf(x) | ((uint)f2bf(y) << 16);
}

// ---------------------------------------------------------------------------
// 0) prep: z=0 transpose Wqkv (768x2304), z=1 transpose Wproj (768x768),
//    z=2 pool (x -> xp bf16). One launch, dim3(72,24,3).
// ---------------------------------------------------------------------------
__global__ __launch_bounds__(256) void prep_kernel(
    const float* __restrict__ Wqkv, ushort* __restrict__ Wq_t,
    const float* __restrict__ Wproj, ushort* __restrict__ Wp_t,
    const float* __restrict__ x, ushort* __restrict__ xp)
{
    __shared__ ushort tile[32][33];
    int z = blockIdx.z;

    if (z == 2) {
        int flatb = blockIdx.y * 72 + blockIdx.x;
        if (flatb >= 1536) return;
        int idx = flatb * 256 + threadIdx.x;        // over B*128*96
        int c8 = idx % 96;
        int t  = idx / 96;
        int i  = t % NPOOL;
        int b  = t / NPOOL;
        if (b >= BB) return;
        const float4* x4 = (const float4*)x;
        size_t base0 = ((size_t)(b * NSEQ + 2 * i)) * 192 + c8 * 2;
        size_t base1 = base0 + 192;
        float4 a0 = x4[base0], a1 = x4[base0 + 1];
        float4 b0 = x4[base1], b1 = x4[base1 + 1];
        uint4 o;
        o.x = pack2(0.5f * (a0.x + b0.x), 0.5f * (a0.y + b0.y));
        o.y = pack2(0.5f * (a0.z + b0.z), 0.5f * (a0.w + b0.w));
        o.z = pack2(0.5f * (a1.x + b1.x), 0.5f * (a1.y + b1.y));
        o.w = pack2(0.5f * (a1.z + b1.z), 0.5f * (a1.w + b1.w));
        ((uint4*)xp)[idx] = o;
        return;
    }

    if (z == 1 && blockIdx.x >= 24) return;
    const float* src = z ? Wproj : Wqkv;
    ushort* dst      = z ? Wp_t  : Wq_t;
    int C = z ? CDIM : 3 * CDIM;
    const int R = CDIM;

    int bc = blockIdx.x * 32, br = blockIdx.y * 32;
    int tx = threadIdx.x & 31, ty = threadIdx.x >> 5;
#pragma unroll
    for (int i = 0; i < 32; i += 8)
        tile[ty + i][tx] = f2bf(src[(size_t)(br + ty + i) * C + bc + tx]);
    __syncthreads();
#pragma unroll
    for (int i = 0; i < 32; i += 8)
        dst[(size_t)(bc + ty + i) * R + br + tx] = tile[tx][ty + i];
}

// ---------------------------------------------------------------------------
// 0b) fp32 -> bf16 bulk convert (R2-proven, verbatim)
// ---------------------------------------------------------------------------
__global__ __launch_bounds__(256) void cvt_bf16_kernel(const float* __restrict__ src,
                                                       ushort* __restrict__ dst, int n8)
{
    int idx = blockIdx.x * 256 + threadIdx.x;
    if (idx >= n8) return;
    float4 a = ((const float4*)src)[idx * 2];
    float4 b = ((const float4*)src)[idx * 2 + 1];
    uint4 o;
    o.x = pack2(a.x, a.y); o.y = pack2(a.z, a.w);
    o.z = pack2(b.x, b.y); o.w = pack2(b.z, b.w);
    ((uint4*)dst)[idx] = o;
}

// ---------------------------------------------------------------------------
// 2a) 128^2-tile bf16 MFMA GEMM (m97 structure, R5-verbatim) — KV proj
// ---------------------------------------------------------------------------
template <bool OBF16>
__global__ __launch_bounds__(256) void mfma_gemm_kernel(
    const ushort* __restrict__ A, const ushort* __restrict__ Bt,
    const float* __restrict__ bias, void* __restrict__ Cout,
    int M, int N, int K)
{
    __shared__ ushort As[128 * 32];
    __shared__ ushort Bs[128 * 32];

    int tid  = threadIdx.x;
    int wave = tid >> 6, lane = tid & 63;

    int nwg  = gridDim.x * gridDim.y;
    int bid  = blockIdx.y * gridDim.x + blockIdx.x;
    int q    = nwg >> 3, r = nwg & 7;
    int xcd  = bid & 7, j = bid >> 3;
    int flat = (xcd < r ? xcd * (q + 1) : r * (q + 1) + (xcd - r) * q) + j;
    int n0 = (flat % gridDim.x) * 128;
    int m0 = (flat / gridDim.x) * 128;

    int wm = wave >> 1, wn = wave & 1;
    int lm = lane & 15, lh = lane >> 4;

    f32x4 acc[4][4] = {};

    for (int k0 = 0; k0 < K; k0 += 32) {
        __syncthreads();
#pragma unroll
        for (int t = 0; t < 2; t++) {
            int fl = wave * 128 + t * 64 + lane;
            int row = fl >> 2, kc = (fl & 3) * 8;
            const ushort* gA = A  + (size_t)(m0 + row) * K + k0 + kc;
            const ushort* gB = Bt + (size_t)(n0 + row) * K + k0 + kc;
            __builtin_amdgcn_global_load_lds(
                (const __attribute__((address_space(1))) void*)gA,
                (__attribute__((address_space(3))) void*)(As + (size_t)(wave * 128 + t * 64) * 8),
                16, 0, 0);
            __builtin_amdgcn_global_load_lds(
                (const __attribute__((address_space(1))) void*)gB,
                (__attribute__((address_space(3))) void*)(Bs + (size_t)(wave * 128 + t * 64) * 8),
                16, 0, 0);
        }
        __syncthreads();

        bf16x8 af[4], bfr[4];
#pragma unroll
        for (int i = 0; i < 4; i++)
            af[i] = *(const bf16x8*)((const void*)&As[(wm * 64 + i * 16 + lm) * 32 + lh * 8]);
#pragma unroll
        for (int jj = 0; jj < 4; jj++)
            bfr[jj] = *(const bf16x8*)((const void*)&Bs[(wn * 64 + jj * 16 + lm) * 32 + lh * 8]);
#pragma unroll
        for (int i = 0; i < 4; i++)
#pragma unroll
            for (int jj = 0; jj < 4; jj++)
                acc[i][jj] = __builtin_amdgcn_mfma_f32_16x16x32_bf16(af[i], bfr[jj], acc[i][jj], 0, 0, 0);
    }

    int crow = m0 + wm * 64, ccol = n0 + wn * 64;
#pragma unroll
    for (int jj = 0; jj < 4; jj++) {
        int col = ccol + jj * 16 + lm;
        float bb = bias[col];
        if constexpr (OBF16) {
            ushort* C = (ushort*)Cout;
#pragma unroll
            for (int i = 0; i < 4; i++)
#pragma unroll
                for (int rr = 0; rr < 4; rr++)
                    C[(size_t)(crow + i * 16 + lh * 4 + rr) * N + col] = f2bf(acc[i][jj][rr] + bb);
        } else {
            float* C = (float*)Cout;
#pragma unroll
            for (int i = 0; i < 4; i++)
#pragma unroll
                for (int rr = 0; rr < 4; rr++)
                    C[(size_t)(crow + i * 16 + lh * 4 + rr) * N + col] = acc[i][jj][rr] + bb;
        }
    }
}

// ---------------------------------------------------------------------------
// 2b) 128x128-tile BK=64 double-buffered GEMM (R5-verbatim structure).
//    bf16 A via global_load_lds, XOR swizzle both-sides, counted vmcnt,
//    setprio. 64 KB LDS -> 2 blocks/CU.
// ---------------------------------------------------------------------------
template <bool OBF16>
__global__ __launch_bounds__(256) void gemm_db_kernel(
    const ushort* __restrict__ A, const ushort* __restrict__ Bt,
    const float* __restrict__ bias, void* __restrict__ Cout,
    int M, int N, int K)
{
    __shared__ ushort As[2][128 * 64];   // 2 x 16 KB
    __shared__ ushort Bs[2][128 * 64];   // 2 x 16 KB

    int tid  = threadIdx.x;
    int lane = tid & 63;
    int wave = tid >> 6;

    int nwg  = gridDim.x * gridDim.y;
    int bid  = blockIdx.y * gridDim.x + blockIdx.x;
    int q    = nwg >> 3, r = nwg & 7;
    int xcd  = bid & 7, jj0 = bid >> 3;
    int flat = (xcd < r ? xcd * (q + 1) : r * (q + 1) + (xcd - r) * q) + jj0;
    int n0 = (flat % gridDim.x) * 128;
    int m0 = (flat / gridDim.x) * 128;

    int wm = wave >> 1, wn = wave & 1;
    int lm = lane & 15, lh = lane >> 4;

    const int NT = K >> 6;

    auto stageB = [&](int tt) {
        int slot = tt & 1;
#pragma unroll
        for (int ld = 0; ld < 4; ld++) {
            int c = ld * 256 + tid;
            int prow = c >> 3, pch = c & 7;
            int lch = pch ^ (prow & 7);
            const ushort* g = Bt + (size_t)(n0 + prow) * K + tt * 64 + lch * 8;
            __builtin_amdgcn_global_load_lds(
                (const __attribute__((address_space(1))) void*)g,
                (__attribute__((address_space(3))) void*)(&Bs[slot][c * 8]),
                16, 0, 0);
        }
    };
    auto stageA16 = [&](int tt) {
        int slot = tt & 1;
#pragma unroll
        for (int ld = 0; ld < 4; ld++) {
            int c = ld * 256 + tid;
            int prow = c >> 3, pch = c & 7;
            int lch = pch ^ (prow & 7);
            const ushort* g = A + (size_t)(m0 + prow) * K + tt * 64 + lch * 8;
            __builtin_amdgcn_global_load_lds(
                (const __attribute__((address_space(1))) void*)g,
                (__attribute__((address_space(3))) void*)(&As[slot][c * 8]),
                16, 0, 0);
        }
    };

    f32x4 acc[4][4] = {};

    auto compute = [&](int slot) {
        bf16x8 bfr[4], af[4];
#pragma unroll
        for (int ks = 0; ks < 2; ks++) {
#pragma unroll
            for (int jj = 0; jj < 4; jj++) {
                int rn = wn * 64 + jj * 16 + lm;
                int ch = (ks * 4 + lh) ^ (rn & 7);
                bfr[jj] = *(const bf16x8*)((const void*)&Bs[slot][rn * 64 + ch * 8]);
            }
#pragma unroll
            for (int i = 0; i < 4; i++) {
                int rm = wm * 64 + i * 16 + lm;
                int ch = (ks * 4 + lh) ^ (rm & 7);
                af[i] = *(const bf16x8*)((const void*)&As[slot][rm * 64 + ch * 8]);
            }
            __builtin_amdgcn_s_setprio(1);
#pragma unroll
            for (int i = 0; i < 4; i++)
#pragma unroll
                for (int jj = 0; jj < 4; jj++)
                    acc[i][jj] = __builtin_amdgcn_mfma_f32_16x16x32_bf16(af[i], bfr[jj], acc[i][jj], 0, 0, 0);
            __builtin_amdgcn_s_setprio(0);
        }
    };

    stageA16(0); stageB(0);
    stageA16(1); stageB(1);
    for (int t = 0; t < NT; t++) {
        int slot = t & 1;
        if (t + 1 < NT) asm volatile("s_waitcnt vmcnt(8)" ::: "memory");
        else            asm volatile("s_waitcnt vmcnt(0)" ::: "memory");
        __builtin_amdgcn_s_barrier();           // tile t resident everywhere
        asm volatile("" ::: "memory");
        compute(slot);
        __builtin_amdgcn_s_barrier();           // reads of [slot] retired
        asm volatile("" ::: "memory");
        if (t + 2 < NT) { stageA16(t + 2); stageB(t + 2); }
    }

    int crow = m0 + wm * 64, ccol = n0 + wn * 64;
#pragma unroll
    for (int jj = 0; jj < 4; jj++) {
        int col = ccol + jj * 16 + lm;
        float bb = bias[col];
        if constexpr (OBF16) {
            ushort* C = (ushort*)Cout;
#pragma unroll
            for (int i = 0; i < 4; i++)
#pragma unroll
                for (int rr = 0; rr < 4; rr++)
                    C[(size_t)(crow + i * 16 + lh * 4 + rr) * N + col] = f2bf(acc[i][jj][rr] + bb);
        } else {
            float* C = (float*)Cout;
#pragma unroll
            for (int i = 0; i < 4; i++)
#pragma unroll
                for (int rr = 0; rr < 4; rr++)
                    C[(size_t)(crow + i * 16 + lh * 4 + rr) * N + col] = acc[i][jj][rr] + bb;
        }
    }
}

// ---------------------------------------------------------------------------
// 3) compress + bank assembly -> bf16 outputs (R5-verbatim)
// ---------------------------------------------------------------------------
__global__ __launch_bounds__(256) void compress_kernel(
    const float* __restrict__ kvp,
    const float* __restrict__ Ek, const float* __restrict__ Ev,
    const float* __restrict__ kbank, const float* __restrict__ vbank,
    ushort* __restrict__ kfull, ushort* __restrict__ vfullT)
{
    __shared__ float Es[128 * 64];
    __shared__ float Sl[128 * 64];

    int tid = threadIdx.x;
    int h = blockIdx.x, b = blockIdx.y, which = blockIdx.z;
    const float* E    = which ? Ev : Ek;
    const float* bank = which ? vbank : kbank;

#pragma unroll
    for (int i = 0; i < 8; i++) {
        int flat = tid + i * 256;
        *(float4*)&Es[flat * 4] = *(const float4*)&E[flat * 4];
    }
    const float* src = kvp + (size_t)b * 128 * 1536 + which * 768 + h * HD;
#pragma unroll
    for (int i = 0; i < 8; i++) {
        int flat = tid + i * 256;
        int s = flat >> 4, d4 = flat & 15;
        *(float4*)&Sl[s * 64 + d4 * 4] = *(const float4*)&src[(size_t)s * 1536 + d4 * 4];
    }

    const float* bankbase = bank + (size_t)b * 64 * CDIM + h * HD;
    ushort* outK = kfull  + (size_t)(b * NH + h) * LKEYS * HD;
    ushort* outV = vfullT + (size_t)(b * NH + h) * HD * LKEYS;

#pragma unroll
    for (int i = 0; i < 4; i++) {
        int flat = tid + i * 256;
        int j = flat >> 4, d4 = flat & 15;
        float4 v = *(const float4*)&bankbase[(size_t)j * CDIM + d4 * 4];
        if (!which) {
            ushort4 o;
            o.x = f2bf(v.x); o.y = f2bf(v.y); o.z = f2bf(v.z); o.w = f2bf(v.w);
            *(ushort4*)&outK[(size_t)(64 + j) * HD + d4 * 4] = o;
        } else {
            outV[(size_t)(d4 * 4 + 0) * LKEYS + 64 + j] = f2bf(v.x);
            outV[(size_t)(d4 * 4 + 1) * LKEYS + 64 + j] = f2bf(v.y);
            outV[(size_t)(d4 * 4 + 2) * LKEYS + 64 + j] = f2bf(v.z);
            outV[(size_t)(d4 * 4 + 3) * LKEYS + 64 + j] = f2bf(v.w);
        }
    }
    __syncthreads();

    int tx = tid & 15, ty = tid >> 4;
    float acc[4][4];
#pragma unroll
    for (int i = 0; i < 4; i++)
#pragma unroll
        for (int j = 0; j < 4; j++) acc[i][j] = 0.f;

#pragma unroll 4
    for (int s = 0; s < 128; s++) {
        float4 av = *(const float4*)&Es[s * 64 + ty * 4];
        float4 bv = *(const float4*)&Sl[s * 64 + tx * 4];
        float a[4] = {av.x, av.y, av.z, av.w};
        float bb[4] = {bv.x, bv.y, bv.z, bv.w};
#pragma unroll
        for (int i = 0; i < 4; i++)
#pragma unroll
            for (int j = 0; j < 4; j++)
                acc[i][j] += a[i] * bb[j];
    }
    if (!which) {
#pragma unroll
        for (int i = 0; i < 4; i++) {
            ushort4 o;
            o.x = f2bf(acc[i][0]); o.y = f2bf(acc[i][1]);
            o.z = f2bf(acc[i][2]); o.w = f2bf(acc[i][3]);
            *(ushort4*)&outK[(size_t)(ty * 4 + i) * HD + tx * 4] = o;
        }
    } else {
#pragma unroll
        for (int i = 0; i < 4; i++)
#pragma unroll
            for (int j = 0; j < 4; j++)
                outV[(size_t)(tx * 4 + j) * LKEYS + ty * 4 + i] = f2bf(acc[i][j]);
    }
}

// ---------------------------------------------------------------------------
// 4) MFMA attention (R5-verbatim)
// ---------------------------------------------------------------------------
__global__ __launch_bounds__(256) void attn_mfma_kernel(
    const ushort* __restrict__ qb, const ushort* __restrict__ kf,
    const ushort* __restrict__ vt, ushort* __restrict__ ob)
{
    __shared__ __align__(16) ushort lds[64 * 72 + 128 * 72 + 64 * 136];
    ushort* Qs = lds;
    ushort* Ks = lds + 64 * 72;
    ushort* Vs = lds + 64 * 72 + 128 * 72;
    ushort* Ps = lds;

    int tid  = threadIdx.x;
    int wave = tid >> 6, lane = tid & 63;
    int lm = lane & 15, lh = lane >> 4;
    int qt = blockIdx.x, h = blockIdx.y, b = blockIdx.z;

    const ushort* qbase = qb + ((size_t)(b * NSEQ + qt * 64)) * CDIM + h * HD;
    const ushort* kbase = kf + (size_t)(b * NH + h) * LKEYS * HD;
    const ushort* vbase = vt + (size_t)(b * NH + h) * HD * LKEYS;

#pragma unroll
    for (int it = 0; it < 2; it++) {
        int flat = tid + it * 256;
        int row = flat >> 3, seg = flat & 7;
        *(uint4*)&Qs[row * 72 + seg * 8] = *(const uint4*)&qbase[(size_t)row * CDIM + seg * 8];
    }
#pragma unroll
    for (int it = 0; it < 4; it++) {
        int flat = tid + it * 256;
        int row = flat >> 3, seg = flat & 7;
        *(uint4*)&Ks[row * 72 + seg * 8] = *(const uint4*)&kbase[(size_t)row * HD + seg * 8];
    }
#pragma unroll
    for (int it = 0; it < 4; it++) {
        int flat = tid + it * 256;
        int row = flat >> 4, seg = flat & 15;
        *(uint4*)&Vs[row * 136 + seg * 8] = *(const uint4*)&vbase[(size_t)row * LKEYS + seg * 8];
    }
    __syncthreads();

    f32x4 sacc[8] = {};
    bf16x8 aq[2];
#pragma unroll
    for (int ks = 0; ks < 2; ks++)
        aq[ks] = *(const bf16x8*)((const void*)&Qs[(wave * 16 + lm) * 72 + ks * 32 + lh * 8]);
#pragma unroll
    for (int j = 0; j < 8; j++)
#pragma unroll
        for (int ks = 0; ks < 2; ks++) {
            bf16x8 bk = *(const bf16x8*)((const void*)&Ks[(j * 16 + lm) * 72 + ks * 32 + lh * 8]);
            sacc[j] = __builtin_amdgcn_mfma_f32_16x16x32_bf16(aq[ks], bk, sacc[j], 0, 0, 0);
        }

    float rinv[4];
#pragma unroll
    for (int r = 0; r < 4; r++) {
        float m = sacc[0][r];
#pragma unroll
        for (int j = 1; j < 8; j++) m = fmaxf(m, sacc[j][r]);
#pragma unroll
        for (int off = 1; off < 16; off <<= 1) m = fmaxf(m, __shfl_xor(m, off, 64));
        float s = 0.f;
#pragma unroll
        for (int j = 0; j < 8; j++) {
            float e = __expf((sacc[j][r] - m) * 0.125f);
            sacc[j][r] = e;
            s += e;
        }
#pragma unroll
        for (int off = 1; off < 16; off <<= 1) s += __shfl_xor(s, off, 64);
        rinv[r] = 1.f / s;
    }

    __syncthreads();
#pragma unroll
    for (int j = 0; j < 8; j++)
#pragma unroll
        for (int r = 0; r < 4; r++)
            Ps[(size_t)(wave * 16 + lh * 4 + r) * 136 + j * 16 + lm] = f2bf(sacc[j][r] * rinv[r]);
    __syncthreads();

    f32x4 oacc[4] = {};
#pragma unroll
    for (int ks = 0; ks < 4; ks++) {
        bf16x8 ap = *(const bf16x8*)((const void*)&Ps[(wave * 16 + lm) * 136 + ks * 32 + lh * 8]);
#pragma unroll
        for (int j = 0; j < 4; j++) {
            bf16x8 bv = *(const bf16x8*)((const void*)&Vs[(j * 16 + lm) * 136 + ks * 32 + lh * 8]);
            oacc[j] = __builtin_amdgcn_mfma_f32_16x16x32_bf16(ap, bv, oacc[j], 0, 0, 0);
        }
    }

    ushort* obase = ob + ((size_t)(b * NSEQ + qt * 64)) * CDIM + h * HD;
#pragma unroll
    for (int j = 0; j < 4; j++)
#pragma unroll
        for (int r = 0; r < 4; r++)
            obase[(size_t)(wave * 16 + lh * 4 + r) * CDIM + j * 16 + lm] = f2bf(oacc[j][r]);
}

// ---------------------------------------------------------------------------
// launch — 6 dispatches: prep -> cvt -> KV -> compress -> Q -> attn -> out
// ---------------------------------------------------------------------------
extern "C" void kernel_launch(void* const* d_in, const int* in_sizes, int n_in,
                              void* d_out, int out_size, void* d_ws, size_t ws_size,
                              hipStream_t stream)
{
    const float* x     = (const float*)d_in[0];
    const float* Wqkv  = (const float*)d_in[1];
    const float* bqkv  = (const float*)d_in[2];
    const float* Ek    = (const float*)d_in[3];
    const float* Ev    = (const float*)d_in[4];
    const float* Wproj = (const float*)d_in[5];
    const float* bproj = (const float*)d_in[6];
    const float* kbank = (const float*)d_in[7];
    const float* vbank = (const float*)d_in[8];
    float* out = (float*)d_out;
    float* ws  = (float*)d_ws;

    // workspace layout (float units) — R2-verbatim aliasing:
    //   kvp (KV gemm -> compress) dies before qb_bf (Q gemm) is written.
    //   x_bf (cvt -> Q gemm) dies before aob (attn out) is written.
    float*  kvp    = ws;                              //  6,291,456 f
    ushort* qb_bf  = (ushort*)ws;                     // 25,165,824 us (alias kvp)
    ushort* x_bf   = (ushort*)(ws + 12582912);        // 25,165,824 us
    ushort* aob    = x_bf;                            // alias (x_bf dead)
    ushort* xp_bf  = (ushort*)(ws + 25165824);        //  3,145,728 us
    ushort* Wq_t   = (ushort*)(ws + 26738688);        //  1,769,472 us (2304 x 768)
    ushort* Wp_t   = (ushort*)(ws + 27623424);        //    589,824 us (768 x 768)
    ushort* k_full = (ushort*)(ws + 27918336);        //  3,145,728 us bf16
    ushort* v_fullT= (ushort*)(ws + 29491200);        //  3,145,728 us bf16 (transposed)

    prep_kernel<<<dim3(72, 24, 3), 256, 0, stream>>>(Wqkv, Wq_t, Wproj, Wp_t, x, xp_bf);
    cvt_bf16_kernel<<<12288, 256, 0, stream>>>(x, x_bf, 3145728);

    // KV projection: 4096 x 1536 (m97 kernel — small grid)
    mfma_gemm_kernel<false><<<dim3(12, 32), 256, 0, stream>>>(
        xp_bf, Wq_t + (size_t)CDIM * CDIM, bqkv + CDIM, kvp, 4096, 2 * CDIM, CDIM);
    compress_kernel<<<dim3(NH, BB, 2), 256, 0, stream>>>(
        kvp, Ek, Ev, kbank, vbank, k_full, v_fullT);

    // Q projection: 32768 x 768, bf16 A via gload_lds, bf16 out
    gemm_db_kernel<true><<<dim3(6, 256), 256, 0, stream>>>(
        x_bf, Wq_t, bqkv, qb_bf, BB * NSEQ, CDIM, CDIM);

    attn_mfma_kernel<<<dim3(16, NH, BB), 256, 0, stream>>>(qb_bf, k_full, v_fullT, aob);

    // output projection: bf16 A via gload_lds, fp32 out
    gemm_db_kernel<false><<<dim3(6, 256), 256, 0, stream>>>(
        aob, Wp_t, bproj, out, BB * NSEQ, CDIM, CDIM);
}